// Round 1
// baseline (727.700 us; speedup 1.0000x reference)
//
#include <hip/hip_runtime.h>

// LDS row pitch in ushorts: multiple of 8 (16B alignment for ds_read_b128),
// 136*2=272B -> dword stride 68 -> bank step 4 -> only 2-way aliasing (free).
#define P 136

typedef __attribute__((ext_vector_type(8))) short short8;
typedef __attribute__((ext_vector_type(4))) float f32x4;

__device__ __forceinline__ unsigned short f2bf(float f) {
  union { float f; unsigned u; } v; v.f = f;
  unsigned u = v.u + 0x7fffu + ((v.u >> 16) & 1u);   // RNE
  return (unsigned short)(u >> 16);
}
__device__ __forceinline__ float bf2f(unsigned short h) {
  union { unsigned u; float f; } v; v.u = ((unsigned)h) << 16;
  return v.f;
}
__device__ __forceinline__ float silu_f(float x) { return x / (1.0f + __expf(-x)); }

// One 2x8-tile (32 rows x 128 cols) MFMA GEMM over K=128.
// sA: [rows][P] bf16 row-major (A: m=lane&15, k=quad*8+j)
// sB: [n][P] bf16 = W^T     (B: n=lane&15, k=quad*8+j)
__device__ __forceinline__ void gemm_32x128x128(const unsigned short* sA,
                                                const unsigned short* sB,
                                                int m0w, int q, int l16,
                                                f32x4 acc[2][8]) {
#pragma unroll
  for (int kt = 0; kt < 4; ++kt) {
    int ko = kt * 32 + q * 8;
    short8 a0 = *(const short8*)&sA[(m0w + l16) * P + ko];
    short8 a1 = *(const short8*)&sA[(m0w + 16 + l16) * P + ko];
#pragma unroll
    for (int ct = 0; ct < 8; ++ct) {
      short8 b = *(const short8*)&sB[(ct * 16 + l16) * P + ko];
      acc[0][ct] = __builtin_amdgcn_mfma_f32_16x16x32_bf16(a0, b, acc[0][ct], 0, 0, 0);
      acc[1][ct] = __builtin_amdgcn_mfma_f32_16x16x32_bf16(a1, b, acc[1][ct], 0, 0, 0);
    }
  }
}

// ---------------------------------------------------------------------------
// Weight folding:  Wn = nw2 @ mw1[:128]   (node_pre = silu(x@nw1+nb1) @ Wn + bn)
//                  Wc = ew2 @ mw1[128:]   (edge contribution folds ew2 away)
// All matrices stored TRANSPOSED ([n][k]) in bf16 for B-operand ds_read_b128.
// ---------------------------------------------------------------------------
__global__ void fold_weights_kernel(
    const float* __restrict__ nw1, const float* __restrict__ nw2,
    const float* __restrict__ nb2, const float* __restrict__ ew2,
    const float* __restrict__ eb2, const float* __restrict__ mw1,
    const float* __restrict__ mb1, const float* __restrict__ mw2,
    const float* __restrict__ uw1, const float* __restrict__ uw2,
    unsigned short* __restrict__ nw1t, unsigned short* __restrict__ wnt,
    unsigned short* __restrict__ wct, unsigned short* __restrict__ mw2t,
    unsigned short* __restrict__ uw1t, unsigned short* __restrict__ uw2t,
    float* __restrict__ bn, float* __restrict__ bc) {
  int b = blockIdx.x;   // n (output col)
  int t = threadIdx.x;  // k (input row)
  float accn = 0.f, accc = 0.f;
  for (int j = 0; j < 128; ++j) {
    accn += nw2[t * 128 + j] * mw1[j * 128 + b];
    accc += ew2[t * 128 + j] * mw1[(128 + j) * 128 + b];
  }
  wnt[b * 128 + t] = f2bf(accn);
  wct[b * 128 + t] = f2bf(accc);
  nw1t[b * 128 + t] = f2bf(nw1[t * 128 + b]);
  mw2t[b * 128 + t] = f2bf(mw2[t * 128 + b]);
  uw1t[b * 128 + t] = f2bf(uw1[t * 128 + b]);
  uw2t[b * 128 + t] = f2bf(uw2[t * 128 + b]);
  if (b == 0) {
    float sn = 0.f, sc = 0.f;
    for (int j = 0; j < 128; ++j) {
      sn += nb2[j] * mw1[j * 128 + t];
      sc += eb2[j] * mw1[(128 + j) * 128 + t];
    }
    bn[t] = sn;
    bc[t] = mb1[t] + sc;
  }
}

// ---------------------------------------------------------------------------
// Node kernel: node_pre = (silu(x@nw1 + nb1)) @ Wn + bn   -> bf16 [N,128]
// 512 threads (8 waves), 256 rows/block, two fused MFMA GEMMs.
// ---------------------------------------------------------------------------
__global__ __launch_bounds__(512, 2) void node_kernel(
    const float* __restrict__ x, const float* __restrict__ nb1,
    const unsigned short* __restrict__ nw1t, const unsigned short* __restrict__ wnt,
    const float* __restrict__ bn, unsigned short* __restrict__ node_pre, int N) {
  __shared__ unsigned short s_w[128 * P];
  __shared__ unsigned short s_x[256 * P];
  __shared__ float s_b1[128];
  __shared__ float s_bn[128];
  int tid = threadIdx.x;
  long base = (long)blockIdx.x * 256;

  // stage x tile as bf16 (coalesced float4 loads)
#pragma unroll
  for (int i = 0; i < 16; ++i) {
    int flat = tid + i * 512;      // 8192 float4 = 256 rows x 32
    int row = flat >> 5;
    int c4 = (flat & 31) << 2;
    float4 v = make_float4(0.f, 0.f, 0.f, 0.f);
    if (base + row < N) v = *(const float4*)&x[(base + row) * 128 + c4];
    unsigned p0 = (unsigned)f2bf(v.x) | ((unsigned)f2bf(v.y) << 16);
    unsigned p1 = (unsigned)f2bf(v.z) | ((unsigned)f2bf(v.w) << 16);
    *(uint2*)&s_x[row * P + c4] = make_uint2(p0, p1);
  }
#pragma unroll
  for (int i = 0; i < 4; ++i) {
    int ch = tid + i * 512;
    int r = ch >> 4, c8 = (ch & 15) << 3;
    *(short8*)&s_w[r * P + c8] = *(const short8*)&nw1t[r * 128 + c8];
  }
  if (tid < 128) { s_b1[tid] = nb1[tid]; s_bn[tid] = bn[tid]; }
  __syncthreads();

  int wave = tid >> 6, lane = tid & 63;
  int q = lane >> 4, l16 = lane & 15;
  int m0w = wave * 32;

  f32x4 acc[2][8];
#pragma unroll
  for (int rt = 0; rt < 2; ++rt)
#pragma unroll
    for (int ct = 0; ct < 8; ++ct) acc[rt][ct] = (f32x4){0.f, 0.f, 0.f, 0.f};
  gemm_32x128x128(s_x, s_w, m0w, q, l16, acc);
  __syncthreads();  // all GEMM1 LDS reads complete

  // h = silu(acc + nb1) -> back into s_x; restage s_w <- Wn^T
#pragma unroll
  for (int rt = 0; rt < 2; ++rt)
#pragma unroll
    for (int r = 0; r < 4; ++r) {
      int m = m0w + rt * 16 + q * 4 + r;
#pragma unroll
      for (int ct = 0; ct < 8; ++ct) {
        int n = ct * 16 + l16;
        s_x[m * P + n] = f2bf(silu_f(acc[rt][ct][r] + s_b1[n]));
      }
    }
#pragma unroll
  for (int i = 0; i < 4; ++i) {
    int ch = tid + i * 512;
    int r = ch >> 4, c8 = (ch & 15) << 3;
    *(short8*)&s_w[r * P + c8] = *(const short8*)&wnt[r * 128 + c8];
  }
  __syncthreads();

  f32x4 acc2[2][8];
#pragma unroll
  for (int rt = 0; rt < 2; ++rt)
#pragma unroll
    for (int ct = 0; ct < 8; ++ct) acc2[rt][ct] = (f32x4){0.f, 0.f, 0.f, 0.f};
  gemm_32x128x128(s_x, s_w, m0w, q, l16, acc2);

#pragma unroll
  for (int rt = 0; rt < 2; ++rt)
#pragma unroll
    for (int r = 0; r < 4; ++r) {
      int m = m0w + rt * 16 + q * 4 + r;
      if (base + m < N) {
#pragma unroll
        for (int ct = 0; ct < 8; ++ct) {
          int n = ct * 16 + l16;
          node_pre[(base + m) * 128 + n] = f2bf(acc2[rt][ct][r] + s_bn[n]);
        }
      }
    }
}

// ---------------------------------------------------------------------------
// Edge kernel: per 256-edge tile:
//   attr = [pos_src, rel_pos @ ori_src]                (VALU)
//   h1   = silu(attr @ ew1 + eb1)                      (VALU, K=6)
//   pre  = h1 @ Wc + bc + node_pre[src]                (MFMA GEMM1 + gather)
//   msg  = silu(pre) @ mw2 + mb2                       (MFMA GEMM2)
//   atomicAdd sums[tgt] += msg ; counts[tgt] += 1
// ---------------------------------------------------------------------------
__global__ __launch_bounds__(512, 2) void edge_kernel(
    const int* __restrict__ eidx, const float* __restrict__ node_pos,
    const float* __restrict__ grid_pos, const float* __restrict__ ori,
    const float* __restrict__ ew1, const float* __restrict__ eb1,
    const unsigned short* __restrict__ wct, const float* __restrict__ bc,
    const unsigned short* __restrict__ mw2t, const float* __restrict__ mb2,
    const unsigned short* __restrict__ node_pre, float* __restrict__ sums,
    float* __restrict__ counts, int E) {
  __shared__ unsigned short s_wc[128 * P];
  __shared__ unsigned short s_w2[128 * P];
  __shared__ unsigned short s_h[256 * P];
  __shared__ float s_attr[256 * 6];
  __shared__ int s_src[256];
  __shared__ int s_tgt[256];
  __shared__ float s_ew1[6 * 128];
  __shared__ float s_eb1[128];
  __shared__ float s_bc[128];
  __shared__ float s_mb2[128];

  int tid = threadIdx.x;
  int base = blockIdx.x * 256;

  // stage both weight matrices (L2-resident) + small tables
#pragma unroll
  for (int i = 0; i < 4; ++i) {
    int ch = tid + i * 512;
    int r = ch >> 4, c8 = (ch & 15) << 3;
    *(short8*)&s_wc[r * P + c8] = *(const short8*)&wct[r * 128 + c8];
    *(short8*)&s_w2[r * P + c8] = *(const short8*)&mw2t[r * 128 + c8];
  }
  for (int i = tid; i < 768; i += 512) s_ew1[i] = ew1[i];
  if (tid < 128) { s_eb1[tid] = eb1[tid]; s_bc[tid] = bc[tid]; s_mb2[tid] = mb2[tid]; }

  // phase 0a: per-edge geometry
  if (tid < 256) {
    int eg = base + tid;
    int s = 0, tg = 0;
    float a0 = 0.f, a1 = 0.f, a2 = 0.f, a3 = 0.f, a4 = 0.f, a5 = 0.f;
    if (eg < E) {
      s = eidx[eg];
      tg = eidx[E + eg];
      float px = node_pos[s * 3 + 0], py = node_pos[s * 3 + 1], pz = node_pos[s * 3 + 2];
      float rx = grid_pos[tg * 3 + 0] - px;
      float ry = grid_pos[tg * 3 + 1] - py;
      float rz = grid_pos[tg * 3 + 2] - pz;
      const float* o = &ori[(long)s * 9];
      a0 = px; a1 = py; a2 = pz;
      a3 = rx * o[0] + ry * o[3] + rz * o[6];
      a4 = rx * o[1] + ry * o[4] + rz * o[7];
      a5 = rx * o[2] + ry * o[5] + rz * o[8];
      atomicAdd(&counts[tg], 1.0f);
    }
    s_src[tid] = s;
    s_tgt[tid] = tg;
    s_attr[tid * 6 + 0] = a0; s_attr[tid * 6 + 1] = a1; s_attr[tid * 6 + 2] = a2;
    s_attr[tid * 6 + 3] = a3; s_attr[tid * 6 + 4] = a4; s_attr[tid * 6 + 5] = a5;
  }
  __syncthreads();

  // phase 0b: h1 = silu(attr @ ew1 + eb1), K=6 on VALU
  {
    int e = tid >> 1;
    int n0 = (tid & 1) * 64;
    float a0 = s_attr[e * 6 + 0], a1 = s_attr[e * 6 + 1], a2 = s_attr[e * 6 + 2];
    float a3 = s_attr[e * 6 + 3], a4 = s_attr[e * 6 + 4], a5 = s_attr[e * 6 + 5];
#pragma unroll 8
    for (int n = n0; n < n0 + 64; n += 2) {
      float v0 = s_eb1[n] + a0 * s_ew1[n] + a1 * s_ew1[128 + n] + a2 * s_ew1[256 + n] +
                 a3 * s_ew1[384 + n] + a4 * s_ew1[512 + n] + a5 * s_ew1[640 + n];
      float v1 = s_eb1[n + 1] + a0 * s_ew1[n + 1] + a1 * s_ew1[129 + n] + a2 * s_ew1[257 + n] +
                 a3 * s_ew1[385 + n] + a4 * s_ew1[513 + n] + a5 * s_ew1[641 + n];
      unsigned pk = (unsigned)f2bf(silu_f(v0)) | ((unsigned)f2bf(silu_f(v1)) << 16);
      *(unsigned*)&s_h[e * P + n] = pk;
    }
  }
  __syncthreads();

  int wave = tid >> 6, lane = tid & 63;
  int q = lane >> 4, l16 = lane & 15;
  int m0w = wave * 32;

  f32x4 acc[2][8];
#pragma unroll
  for (int rt = 0; rt < 2; ++rt)
#pragma unroll
    for (int ct = 0; ct < 8; ++ct) acc[rt][ct] = (f32x4){0.f, 0.f, 0.f, 0.f};
  gemm_32x128x128(s_h, s_wc, m0w, q, l16, acc);

  // gather node_pre[src] + bias, SiLU (in registers)
#pragma unroll
  for (int rt = 0; rt < 2; ++rt)
#pragma unroll
    for (int r = 0; r < 4; ++r) {
      int m = m0w + rt * 16 + q * 4 + r;
      long srow = (long)s_src[m] * 128;
#pragma unroll
      for (int ct = 0; ct < 8; ++ct) {
        int n = ct * 16 + l16;
        float pre = acc[rt][ct][r] + s_bc[n] + bf2f(node_pre[srow + n]);
        acc[rt][ct][r] = silu_f(pre);
      }
    }
  __syncthreads();  // all GEMM1 reads of s_h done

  // write h2 back into s_h
#pragma unroll
  for (int rt = 0; rt < 2; ++rt)
#pragma unroll
    for (int r = 0; r < 4; ++r) {
      int m = m0w + rt * 16 + q * 4 + r;
#pragma unroll
      for (int ct = 0; ct < 8; ++ct) s_h[m * P + ct * 16 + l16] = f2bf(acc[rt][ct][r]);
    }
  __syncthreads();

  f32x4 acc2[2][8];
#pragma unroll
  for (int rt = 0; rt < 2; ++rt)
#pragma unroll
    for (int ct = 0; ct < 8; ++ct) acc2[rt][ct] = (f32x4){0.f, 0.f, 0.f, 0.f};
  gemm_32x128x128(s_h, s_w2, m0w, q, l16, acc2);

  // scatter-add messages
#pragma unroll
  for (int rt = 0; rt < 2; ++rt)
#pragma unroll
    for (int r = 0; r < 4; ++r) {
      int m = m0w + rt * 16 + q * 4 + r;
      if (base + m < E) {
        long trow = (long)s_tgt[m] * 128;
#pragma unroll
        for (int ct = 0; ct < 8; ++ct) {
          int n = ct * 16 + l16;
          atomicAdd(&sums[trow + n], acc2[rt][ct][r] + s_mb2[n]);
        }
      }
    }
}

// ---------------------------------------------------------------------------
// Grid kernel: out = MLP(sums/clip(counts,1), uw1,ub1,uw2,ub2)  fp32 out
// ---------------------------------------------------------------------------
__global__ __launch_bounds__(512, 2) void grid_kernel(
    const float* __restrict__ sums, const float* __restrict__ counts,
    const float* __restrict__ ub1, const float* __restrict__ ub2,
    const unsigned short* __restrict__ uw1t, const unsigned short* __restrict__ uw2t,
    float* __restrict__ out, int G) {
  __shared__ unsigned short s_w[128 * P];
  __shared__ unsigned short s_x[256 * P];
  __shared__ float s_b1[128];
  __shared__ float s_b2[128];
  int tid = threadIdx.x;
  long base = (long)blockIdx.x * 256;

#pragma unroll
  for (int i = 0; i < 16; ++i) {
    int flat = tid + i * 512;
    int row = flat >> 5;
    int c4 = (flat & 31) << 2;
    float4 v = make_float4(0.f, 0.f, 0.f, 0.f);
    float inv = 1.f;
    if (base + row < G) {
      v = *(const float4*)&sums[(base + row) * 128 + c4];
      float c = counts[base + row];
      inv = 1.f / (c < 1.f ? 1.f : c);
    }
    unsigned p0 = (unsigned)f2bf(v.x * inv) | ((unsigned)f2bf(v.y * inv) << 16);
    unsigned p1 = (unsigned)f2bf(v.z * inv) | ((unsigned)f2bf(v.w * inv) << 16);
    *(uint2*)&s_x[row * P + c4] = make_uint2(p0, p1);
  }
#pragma unroll
  for (int i = 0; i < 4; ++i) {
    int ch = tid + i * 512;
    int r = ch >> 4, c8 = (ch & 15) << 3;
    *(short8*)&s_w[r * P + c8] = *(const short8*)&uw1t[r * 128 + c8];
  }
  if (tid < 128) { s_b1[tid] = ub1[tid]; s_b2[tid] = ub2[tid]; }
  __syncthreads();

  int wave = tid >> 6, lane = tid & 63;
  int q = lane >> 4, l16 = lane & 15;
  int m0w = wave * 32;

  f32x4 acc[2][8];
#pragma unroll
  for (int rt = 0; rt < 2; ++rt)
#pragma unroll
    for (int ct = 0; ct < 8; ++ct) acc[rt][ct] = (f32x4){0.f, 0.f, 0.f, 0.f};
  gemm_32x128x128(s_x, s_w, m0w, q, l16, acc);
  __syncthreads();

#pragma unroll
  for (int rt = 0; rt < 2; ++rt)
#pragma unroll
    for (int r = 0; r < 4; ++r) {
      int m = m0w + rt * 16 + q * 4 + r;
#pragma unroll
      for (int ct = 0; ct < 8; ++ct) {
        int n = ct * 16 + l16;
        s_x[m * P + n] = f2bf(silu_f(acc[rt][ct][r] + s_b1[n]));
      }
    }
#pragma unroll
  for (int i = 0; i < 4; ++i) {
    int ch = tid + i * 512;
    int r = ch >> 4, c8 = (ch & 15) << 3;
    *(short8*)&s_w[r * P + c8] = *(const short8*)&uw2t[r * 128 + c8];
  }
  __syncthreads();

  f32x4 acc2[2][8];
#pragma unroll
  for (int rt = 0; rt < 2; ++rt)
#pragma unroll
    for (int ct = 0; ct < 8; ++ct) acc2[rt][ct] = (f32x4){0.f, 0.f, 0.f, 0.f};
  gemm_32x128x128(s_x, s_w, m0w, q, l16, acc2);

#pragma unroll
  for (int rt = 0; rt < 2; ++rt)
#pragma unroll
    for (int r = 0; r < 4; ++r) {
      int m = m0w + rt * 16 + q * 4 + r;
      if (base + m < G) {
#pragma unroll
        for (int ct = 0; ct < 8; ++ct) {
          int n = ct * 16 + l16;
          out[(base + m) * 128 + n] = acc2[rt][ct][r] + s_b2[n];
        }
      }
    }
}

extern "C" void kernel_launch(void* const* d_in, const int* in_sizes, int n_in,
                              void* d_out, int out_size, void* d_ws, size_t ws_size,
                              hipStream_t stream) {
  const float* x    = (const float*)d_in[0];
  const float* npos = (const float*)d_in[1];
  const float* gpos = (const float*)d_in[2];
  const int*   eidx = (const int*)d_in[3];
  const float* ori  = (const float*)d_in[4];
  const float* nw1 = (const float*)d_in[5];
  const float* nb1 = (const float*)d_in[6];
  const float* nw2 = (const float*)d_in[7];
  const float* nb2 = (const float*)d_in[8];
  const float* ew1 = (const float*)d_in[9];
  const float* eb1 = (const float*)d_in[10];
  const float* ew2 = (const float*)d_in[11];
  const float* eb2 = (const float*)d_in[12];
  const float* mw1 = (const float*)d_in[13];
  const float* mb1 = (const float*)d_in[14];
  const float* mw2 = (const float*)d_in[15];
  const float* mb2 = (const float*)d_in[16];
  const float* uw1 = (const float*)d_in[17];
  const float* ub1 = (const float*)d_in[18];
  const float* uw2 = (const float*)d_in[19];
  const float* ub2 = (const float*)d_in[20];

  int N = in_sizes[0] / 128;
  int G = in_sizes[2] / 3;
  int E = in_sizes[3] / 2;

  char* ws = (char*)d_ws;
  size_t off = 0;
  float* sums = (float*)(ws + off);           off += (size_t)G * 128 * 4;
  float* counts = (float*)(ws + off);         off += (size_t)G * 4;
  unsigned short* node_pre = (unsigned short*)(ws + off); off += (size_t)N * 128 * 2;
  off = (off + 255) & ~(size_t)255;
  unsigned short* w_nw1t = (unsigned short*)(ws + off); off += 128 * 128 * 2;
  unsigned short* w_wnt  = (unsigned short*)(ws + off); off += 128 * 128 * 2;
  unsigned short* w_wct  = (unsigned short*)(ws + off); off += 128 * 128 * 2;
  unsigned short* w_mw2t = (unsigned short*)(ws + off); off += 128 * 128 * 2;
  unsigned short* w_uw1t = (unsigned short*)(ws + off); off += 128 * 128 * 2;
  unsigned short* w_uw2t = (unsigned short*)(ws + off); off += 128 * 128 * 2;
  float* bn = (float*)(ws + off); off += 128 * 4;
  float* bc = (float*)(ws + off); off += 128 * 4;

  // zero sums + counts (contiguous)
  hipMemsetAsync(sums, 0, ((size_t)G * 128 + G) * 4, stream);

  fold_weights_kernel<<<128, 128, 0, stream>>>(nw1, nw2, nb2, ew2, eb2, mw1, mb1,
                                               mw2, uw1, uw2, w_nw1t, w_wnt, w_wct,
                                               w_mw2t, w_uw1t, w_uw2t, bn, bc);
  node_kernel<<<(N + 255) / 256, 512, 0, stream>>>(x, nb1, w_nw1t, w_wnt, bn,
                                                   node_pre, N);
  edge_kernel<<<(E + 255) / 256, 512, 0, stream>>>(eidx, npos, gpos, ori, ew1, eb1,
                                                   w_wct, bc, w_mw2t, mb2, node_pre,
                                                   sums, counts, E);
  grid_kernel<<<(G + 255) / 256, 512, 0, stream>>>(sums, counts, ub1, ub2, w_uw1t,
                                                   w_uw2t, (float*)d_out, G);
}

// Round 3
// 652.077 us; speedup vs baseline: 1.1160x; 1.1160x over previous
//
#include <hip/hip_runtime.h>

// LDS row pitch in ushorts: multiple of 8 (16B alignment for ds_read_b128),
// 136*2=272B -> dword stride 68 -> bank step 4 -> only 2-way aliasing (free).
#define P 136

typedef __attribute__((ext_vector_type(8))) short short8;
typedef __attribute__((ext_vector_type(4))) float f32x4;

__device__ __forceinline__ unsigned short f2bf(float f) {
  union { float f; unsigned u; } v; v.f = f;
  unsigned u = v.u + 0x7fffu + ((v.u >> 16) & 1u);   // RNE
  return (unsigned short)(u >> 16);
}
__device__ __forceinline__ float bf2f(unsigned short h) {
  union { unsigned u; float f; } v; v.u = ((unsigned)h) << 16;
  return v.f;
}
__device__ __forceinline__ float silu_f(float x) { return x / (1.0f + __expf(-x)); }

// One 2x8-tile (32 rows x 128 cols) MFMA GEMM over K=128.
__device__ __forceinline__ void gemm_32x128x128(const unsigned short* sA,
                                                const unsigned short* sB,
                                                int m0w, int q, int l16,
                                                f32x4 acc[2][8]) {
#pragma unroll
  for (int kt = 0; kt < 4; ++kt) {
    int ko = kt * 32 + q * 8;
    short8 a0 = *(const short8*)&sA[(m0w + l16) * P + ko];
    short8 a1 = *(const short8*)&sA[(m0w + 16 + l16) * P + ko];
#pragma unroll
    for (int ct = 0; ct < 8; ++ct) {
      short8 b = *(const short8*)&sB[(ct * 16 + l16) * P + ko];
      acc[0][ct] = __builtin_amdgcn_mfma_f32_16x16x32_bf16(a0, b, acc[0][ct], 0, 0, 0);
      acc[1][ct] = __builtin_amdgcn_mfma_f32_16x16x32_bf16(a1, b, acc[1][ct], 0, 0, 0);
    }
  }
}

// ---------------------------------------------------------------------------
// Weight folding:  Wn = nw2 @ mw1[:128], Wc = ew2 @ mw1[128:]
// ---------------------------------------------------------------------------
__global__ void fold_weights_kernel(
    const float* __restrict__ nw1, const float* __restrict__ nw2,
    const float* __restrict__ nb2, const float* __restrict__ ew2,
    const float* __restrict__ eb2, const float* __restrict__ mw1,
    const float* __restrict__ mb1, const float* __restrict__ mw2,
    const float* __restrict__ uw1, const float* __restrict__ uw2,
    unsigned short* __restrict__ nw1t, unsigned short* __restrict__ wnt,
    unsigned short* __restrict__ wct, unsigned short* __restrict__ mw2t,
    unsigned short* __restrict__ uw1t, unsigned short* __restrict__ uw2t,
    float* __restrict__ bn, float* __restrict__ bc) {
  int b = blockIdx.x;   // n (output col)
  int t = threadIdx.x;  // k (input row)
  float accn = 0.f, accc = 0.f;
  for (int j = 0; j < 128; ++j) {
    accn += nw2[t * 128 + j] * mw1[j * 128 + b];
    accc += ew2[t * 128 + j] * mw1[(128 + j) * 128 + b];
  }
  wnt[b * 128 + t] = f2bf(accn);
  wct[b * 128 + t] = f2bf(accc);
  nw1t[b * 128 + t] = f2bf(nw1[t * 128 + b]);
  mw2t[b * 128 + t] = f2bf(mw2[t * 128 + b]);
  uw1t[b * 128 + t] = f2bf(uw1[t * 128 + b]);
  uw2t[b * 128 + t] = f2bf(uw2[t * 128 + b]);
  if (b == 0) {
    float sn = 0.f, sc = 0.f;
    for (int j = 0; j < 128; ++j) {
      sn += nb2[j] * mw1[j * 128 + t];
      sc += eb2[j] * mw1[(128 + j) * 128 + t];
    }
    bn[t] = sn;
    bc[t] = mb1[t] + sc;
  }
}

// ---------------------------------------------------------------------------
// Sort scaffolding: histogram of tgt, prefix scan, scatter of (src,tgt).
// ---------------------------------------------------------------------------
__global__ void hist_kernel(const int* __restrict__ eidx, int* __restrict__ hist,
                            int E) {
  int e = blockIdx.x * blockDim.x + threadIdx.x;
  if (e < E) atomicAdd(&hist[eidx[E + e]], 1);
}

__global__ __launch_bounds__(1024) void scan_kernel(const int* __restrict__ hist,
                                                    int* __restrict__ cursor, int G) {
  __shared__ int s[1024];
  int tid = threadIdx.x;
  int per = (G + 1023) >> 10;
  int b0 = tid * per;
  int sum = 0;
  for (int i = 0; i < per; ++i)
    if (b0 + i < G) sum += hist[b0 + i];
  s[tid] = sum;
  __syncthreads();
  for (int off = 1; off < 1024; off <<= 1) {
    int v = (tid >= off) ? s[tid - off] : 0;
    __syncthreads();
    s[tid] += v;
    __syncthreads();
  }
  int run = s[tid] - sum;  // exclusive prefix
  for (int i = 0; i < per; ++i)
    if (b0 + i < G) {
      cursor[b0 + i] = run;
      run += hist[b0 + i];
    }
}

__global__ void scatter_kernel(const int* __restrict__ eidx, int* __restrict__ cursor,
                               int2* __restrict__ st, int E) {
  int e = blockIdx.x * blockDim.x + threadIdx.x;
  if (e < E) {
    int tg = eidx[E + e];
    int pos = atomicAdd(&cursor[tg], 1);
    st[pos] = make_int2(eidx[e], tg);
  }
}

// ---------------------------------------------------------------------------
// Node kernel: node_pre = (silu(x@nw1 + nb1)) @ Wn + bn   -> bf16 [N,128]
// ---------------------------------------------------------------------------
__global__ __launch_bounds__(512, 2) void node_kernel(
    const float* __restrict__ x, const float* __restrict__ nb1,
    const unsigned short* __restrict__ nw1t, const unsigned short* __restrict__ wnt,
    const float* __restrict__ bn, unsigned short* __restrict__ node_pre, int N) {
  __shared__ unsigned short s_w[128 * P];
  __shared__ unsigned short s_x[256 * P];
  __shared__ float s_b1[128];
  __shared__ float s_bn[128];
  int tid = threadIdx.x;
  long base = (long)blockIdx.x * 256;

#pragma unroll
  for (int i = 0; i < 16; ++i) {
    int flat = tid + i * 512;
    int row = flat >> 5;
    int c4 = (flat & 31) << 2;
    float4 v = make_float4(0.f, 0.f, 0.f, 0.f);
    if (base + row < N) v = *(const float4*)&x[(base + row) * 128 + c4];
    unsigned p0 = (unsigned)f2bf(v.x) | ((unsigned)f2bf(v.y) << 16);
    unsigned p1 = (unsigned)f2bf(v.z) | ((unsigned)f2bf(v.w) << 16);
    *(uint2*)&s_x[row * P + c4] = make_uint2(p0, p1);
  }
#pragma unroll
  for (int i = 0; i < 4; ++i) {
    int ch = tid + i * 512;
    int r = ch >> 4, c8 = (ch & 15) << 3;
    *(short8*)&s_w[r * P + c8] = *(const short8*)&nw1t[r * 128 + c8];
  }
  if (tid < 128) { s_b1[tid] = nb1[tid]; s_bn[tid] = bn[tid]; }
  __syncthreads();

  int wave = tid >> 6, lane = tid & 63;
  int q = lane >> 4, l16 = lane & 15;
  int m0w = wave * 32;

  f32x4 acc[2][8];
#pragma unroll
  for (int rt = 0; rt < 2; ++rt)
#pragma unroll
    for (int ct = 0; ct < 8; ++ct) acc[rt][ct] = (f32x4){0.f, 0.f, 0.f, 0.f};
  gemm_32x128x128(s_x, s_w, m0w, q, l16, acc);
  __syncthreads();

#pragma unroll
  for (int rt = 0; rt < 2; ++rt)
#pragma unroll
    for (int r = 0; r < 4; ++r) {
      int m = m0w + rt * 16 + q * 4 + r;
#pragma unroll
      for (int ct = 0; ct < 8; ++ct) {
        int n = ct * 16 + l16;
        s_x[m * P + n] = f2bf(silu_f(acc[rt][ct][r] + s_b1[n]));
      }
    }
#pragma unroll
  for (int i = 0; i < 4; ++i) {
    int ch = tid + i * 512;
    int r = ch >> 4, c8 = (ch & 15) << 3;
    *(short8*)&s_w[r * P + c8] = *(const short8*)&wnt[r * 128 + c8];
  }
  __syncthreads();

  f32x4 acc2[2][8];
#pragma unroll
  for (int rt = 0; rt < 2; ++rt)
#pragma unroll
    for (int ct = 0; ct < 8; ++ct) acc2[rt][ct] = (f32x4){0.f, 0.f, 0.f, 0.f};
  gemm_32x128x128(s_x, s_w, m0w, q, l16, acc2);

#pragma unroll
  for (int rt = 0; rt < 2; ++rt)
#pragma unroll
    for (int r = 0; r < 4; ++r) {
      int m = m0w + rt * 16 + q * 4 + r;
      if (base + m < N) {
#pragma unroll
        for (int ct = 0; ct < 8; ++ct) {
          int n = ct * 16 + l16;
          node_pre[(base + m) * 128 + n] = f2bf(acc2[rt][ct][r] + s_bn[n]);
        }
      }
    }
}

// ---------------------------------------------------------------------------
// Edge kernel (sorted edges). Per 256-slot block:
//   attr (bf16, K=32-padded) --MFMA--> h1=silu(.+eb1)
//   h1 @ Wc + bc + node_pre[src] --silu--> h2
//   segmented reduction over tgt runs -> atomicAdd into sums (h2-space!)
// mw2 is applied later in grid_kernel (linearity of mean).
// ---------------------------------------------------------------------------
__global__ __launch_bounds__(512, 2) void edge_kernel(
    const int2* __restrict__ st_sorted, const float* __restrict__ node_pos,
    const float* __restrict__ grid_pos, const float* __restrict__ ori,
    const float* __restrict__ ew1, const float* __restrict__ eb1,
    const unsigned short* __restrict__ wct, const float* __restrict__ bc,
    const unsigned short* __restrict__ node_pre, float* __restrict__ sums, int E) {
  __shared__ unsigned short s_wc[128 * P];
  __shared__ unsigned short s_e1[128 * 40];   // ew1^T, K=32 zero-padded
  __shared__ unsigned short s_h[256 * P];
  __shared__ int s_src[256];
  __shared__ int s_tgt[256];
  __shared__ float s_eb1[128];
  __shared__ float s_bc[128];

  int tid = threadIdx.x;
  int base = blockIdx.x * 256;

#pragma unroll
  for (int i = 0; i < 4; ++i) {
    int ch = tid + i * 512;
    int r = ch >> 4, c8 = (ch & 15) << 3;
    *(short8*)&s_wc[r * P + c8] = *(const short8*)&wct[r * 128 + c8];
  }
  for (int i = tid; i < 4096; i += 512) {
    int n = i >> 5, k = i & 31;
    s_e1[n * 40 + k] = (k < 6) ? f2bf(ew1[k * 128 + n]) : (unsigned short)0;
  }
  if (tid < 128) { s_eb1[tid] = eb1[tid]; s_bc[tid] = bc[tid]; }

  // geometry -> attr (bf16, zero-padded to K=32) into s_h cols [0,32)
  if (tid < 256) {
    int eg = base + tid;
    int s = 0, tg = -1;
    float a0 = 0.f, a1 = 0.f, a2 = 0.f, a3 = 0.f, a4 = 0.f, a5 = 0.f;
    if (eg < E) {
      int2 st = st_sorted[eg];
      s = st.x; tg = st.y;
      float px = node_pos[s * 3 + 0], py = node_pos[s * 3 + 1], pz = node_pos[s * 3 + 2];
      float rx = grid_pos[tg * 3 + 0] - px;
      float ry = grid_pos[tg * 3 + 1] - py;
      float rz = grid_pos[tg * 3 + 2] - pz;
      const float* o = &ori[(long)s * 9];
      a0 = px; a1 = py; a2 = pz;
      a3 = rx * o[0] + ry * o[3] + rz * o[6];
      a4 = rx * o[1] + ry * o[4] + rz * o[7];
      a5 = rx * o[2] + ry * o[5] + rz * o[8];
    }
    s_src[tid] = s;
    s_tgt[tid] = tg;
    uint4 w0;
    w0.x = (unsigned)f2bf(a0) | ((unsigned)f2bf(a1) << 16);
    w0.y = (unsigned)f2bf(a2) | ((unsigned)f2bf(a3) << 16);
    w0.z = (unsigned)f2bf(a4) | ((unsigned)f2bf(a5) << 16);
    w0.w = 0u;
    uint4 z = make_uint4(0u, 0u, 0u, 0u);
    *(uint4*)&s_h[tid * P + 0] = w0;
    *(uint4*)&s_h[tid * P + 8] = z;
    *(uint4*)&s_h[tid * P + 16] = z;
    *(uint4*)&s_h[tid * P + 24] = z;
  }
  __syncthreads();

  int wave = tid >> 6, lane = tid & 63;
  int q = lane >> 4, l16 = lane & 15;
  int m0w = wave * 32;

  // GEMM0: attr(K=32) @ ew1 -> h1
  f32x4 acc0[2][8];
#pragma unroll
  for (int rt = 0; rt < 2; ++rt)
#pragma unroll
    for (int ct = 0; ct < 8; ++ct) acc0[rt][ct] = (f32x4){0.f, 0.f, 0.f, 0.f};
  {
    short8 a0 = *(const short8*)&s_h[(m0w + l16) * P + q * 8];
    short8 a1 = *(const short8*)&s_h[(m0w + 16 + l16) * P + q * 8];
#pragma unroll
    for (int ct = 0; ct < 8; ++ct) {
      short8 b = *(const short8*)&s_e1[(ct * 16 + l16) * 40 + q * 8];
      acc0[0][ct] = __builtin_amdgcn_mfma_f32_16x16x32_bf16(a0, b, acc0[0][ct], 0, 0, 0);
      acc0[1][ct] = __builtin_amdgcn_mfma_f32_16x16x32_bf16(a1, b, acc0[1][ct], 0, 0, 0);
    }
  }
  __syncthreads();  // GEMM0 reads of s_h done before overwrite

  // h1 = silu(acc0 + eb1) -> s_h
#pragma unroll
  for (int rt = 0; rt < 2; ++rt)
#pragma unroll
    for (int r = 0; r < 4; ++r) {
      int m = m0w + rt * 16 + q * 4 + r;
#pragma unroll
      for (int ct = 0; ct < 8; ++ct) {
        int n = ct * 16 + l16;
        s_h[m * P + n] = f2bf(silu_f(acc0[rt][ct][r] + s_eb1[n]));
      }
    }
  __syncthreads();

  // GEMM1: h1 @ Wc
  f32x4 acc[2][8];
#pragma unroll
  for (int rt = 0; rt < 2; ++rt)
#pragma unroll
    for (int ct = 0; ct < 8; ++ct) acc[rt][ct] = (f32x4){0.f, 0.f, 0.f, 0.f};
  gemm_32x128x128(s_h, s_wc, m0w, q, l16, acc);

  // + node_pre[src] + bc, silu -> h2
#pragma unroll
  for (int rt = 0; rt < 2; ++rt)
#pragma unroll
    for (int r = 0; r < 4; ++r) {
      int m = m0w + rt * 16 + q * 4 + r;
      long srow = (long)s_src[m] * 128;
#pragma unroll
      for (int ct = 0; ct < 8; ++ct) {
        int n = ct * 16 + l16;
        float pre = acc[rt][ct][r] + s_bc[n] + bf2f(node_pre[srow + n]);
        acc[rt][ct][r] = silu_f(pre);
      }
    }
  __syncthreads();  // GEMM1 reads of s_h done

#pragma unroll
  for (int rt = 0; rt < 2; ++rt)
#pragma unroll
    for (int r = 0; r < 4; ++r) {
      int m = m0w + rt * 16 + q * 4 + r;
#pragma unroll
      for (int ct = 0; ct < 8; ++ct) s_h[m * P + ct * 16 + l16] = f2bf(acc[rt][ct][r]);
    }
  __syncthreads();

  // segmented reduction: thread = (colpair, 32-row chunk); runs are
  // wave-uniform (chunk == wave>>... chunk per 64-thread group) so the
  // flush branch is wave-uniform.
  {
    int cp = tid & 63;
    int chunk = tid >> 6;
    int c0 = cp * 2;
    int row0 = chunk * 32;
    float v0 = 0.f, v1 = 0.f;
    int cur = s_tgt[row0];
    for (int r = 0; r < 32; ++r) {
      int row = row0 + r;
      int tg = s_tgt[row];
      if (tg != cur) {
        if (cur >= 0) {
          atomicAdd(&sums[(long)cur * 128 + c0], v0);
          atomicAdd(&sums[(long)cur * 128 + c0 + 1], v1);
        }
        v0 = 0.f; v1 = 0.f; cur = tg;
      }
      unsigned w = *(const unsigned*)&s_h[row * P + c0];
      v0 += bf2f((unsigned short)w);
      v1 += bf2f((unsigned short)(w >> 16));
    }
    if (cur >= 0) {
      atomicAdd(&sums[(long)cur * 128 + c0], v0);
      atomicAdd(&sums[(long)cur * 128 + c0 + 1], v1);
    }
  }
}

// ---------------------------------------------------------------------------
// Grid kernel: x = sums/clip(hist,1);  y = x@mw2 + mb2 (grid_feat);
//              out = silu(y@uw1+ub1)@uw2 + ub2
// 128 rows/block, 256 threads -> 256 blocks.
// ---------------------------------------------------------------------------
__global__ __launch_bounds__(256, 2) void grid_kernel(
    const float* __restrict__ sums, const int* __restrict__ hist,
    const float* __restrict__ mb2, const float* __restrict__ ub1,
    const float* __restrict__ ub2, const unsigned short* __restrict__ mw2t,
    const unsigned short* __restrict__ uw1t, const unsigned short* __restrict__ uw2t,
    float* __restrict__ out, int G) {
  __shared__ unsigned short s_w[128 * P];
  __shared__ unsigned short s_x[128 * P];
  __shared__ float s_bm[128];
  __shared__ float s_b1[128];
  __shared__ float s_b2[128];
  int tid = threadIdx.x;
  long base = (long)blockIdx.x * 128;

#pragma unroll
  for (int i = 0; i < 16; ++i) {
    int flat = tid + i * 256;       // 4096 float4 = 128 rows x 32
    int row = flat >> 5;
    int c4 = (flat & 31) << 2;
    float4 v = make_float4(0.f, 0.f, 0.f, 0.f);
    float inv = 1.f;
    if (base + row < G) {
      v = *(const float4*)&sums[(base + row) * 128 + c4];
      int c = hist[base + row];
      inv = 1.f / (float)(c < 1 ? 1 : c);
    }
    unsigned p0 = (unsigned)f2bf(v.x * inv) | ((unsigned)f2bf(v.y * inv) << 16);
    unsigned p1 = (unsigned)f2bf(v.z * inv) | ((unsigned)f2bf(v.w * inv) << 16);
    *(uint2*)&s_x[row * P + c4] = make_uint2(p0, p1);
  }
#pragma unroll
  for (int i = 0; i < 8; ++i) {
    int ch = tid + i * 256;
    int r = ch >> 4, c8 = (ch & 15) << 3;
    *(short8*)&s_w[r * P + c8] = *(const short8*)&mw2t[r * 128 + c8];
  }
  if (tid < 128) { s_bm[tid] = mb2[tid]; s_b1[tid] = ub1[tid]; s_b2[tid] = ub2[tid]; }
  __syncthreads();

  int wave = tid >> 6, lane = tid & 63;
  int q = lane >> 4, l16 = lane & 15;
  int m0w = wave * 32;

  // GEMM A: grid_feat = x@mw2 + mb2  (no activation)
  f32x4 acc[2][8];
#pragma unroll
  for (int rt = 0; rt < 2; ++rt)
#pragma unroll
    for (int ct = 0; ct < 8; ++ct) acc[rt][ct] = (f32x4){0.f, 0.f, 0.f, 0.f};
  gemm_32x128x128(s_x, s_w, m0w, q, l16, acc);
  __syncthreads();
#pragma unroll
  for (int rt = 0; rt < 2; ++rt)
#pragma unroll
    for (int r = 0; r < 4; ++r) {
      int m = m0w + rt * 16 + q * 4 + r;
#pragma unroll
      for (int ct = 0; ct < 8; ++ct) {
        int n = ct * 16 + l16;
        s_x[m * P + n] = f2bf(acc[rt][ct][r] + s_bm[n]);
      }
    }
#pragma unroll
  for (int i = 0; i < 8; ++i) {
    int ch = tid + i * 256;
    int r = ch >> 4, c8 = (ch & 15) << 3;
    *(short8*)&s_w[r * P + c8] = *(const short8*)&uw1t[r * 128 + c8];
  }
  __syncthreads();

  // GEMM B: silu(y@uw1 + ub1)
#pragma unroll
  for (int rt = 0; rt < 2; ++rt)
#pragma unroll
    for (int ct = 0; ct < 8; ++ct) acc[rt][ct] = (f32x4){0.f, 0.f, 0.f, 0.f};
  gemm_32x128x128(s_x, s_w, m0w, q, l16, acc);
  __syncthreads();
#pragma unroll
  for (int rt = 0; rt < 2; ++rt)
#pragma unroll
    for (int r = 0; r < 4; ++r) {
      int m = m0w + rt * 16 + q * 4 + r;
#pragma unroll
      for (int ct = 0; ct < 8; ++ct) {
        int n = ct * 16 + l16;
        s_x[m * P + n] = f2bf(silu_f(acc[rt][ct][r] + s_b1[n]));
      }
    }
#pragma unroll
  for (int i = 0; i < 8; ++i) {
    int ch = tid + i * 256;
    int r = ch >> 4, c8 = (ch & 15) << 3;
    *(short8*)&s_w[r * P + c8] = *(const short8*)&uw2t[r * 128 + c8];
  }
  __syncthreads();

  // GEMM C: out = h@uw2 + ub2
#pragma unroll
  for (int rt = 0; rt < 2; ++rt)
#pragma unroll
    for (int ct = 0; ct < 8; ++ct) acc[rt][ct] = (f32x4){0.f, 0.f, 0.f, 0.f};
  gemm_32x128x128(s_x, s_w, m0w, q, l16, acc);

#pragma unroll
  for (int rt = 0; rt < 2; ++rt)
#pragma unroll
    for (int r = 0; r < 4; ++r) {
      int m = m0w + rt * 16 + q * 4 + r;
      if (base + m < G) {
#pragma unroll
        for (int ct = 0; ct < 8; ++ct) {
          int n = ct * 16 + l16;
          out[(base + m) * 128 + n] = acc[rt][ct][r] + s_b2[n];
        }
      }
    }
}

extern "C" void kernel_launch(void* const* d_in, const int* in_sizes, int n_in,
                              void* d_out, int out_size, void* d_ws, size_t ws_size,
                              hipStream_t stream) {
  const float* x    = (const float*)d_in[0];
  const float* npos = (const float*)d_in[1];
  const float* gpos = (const float*)d_in[2];
  const int*   eidx = (const int*)d_in[3];
  const float* ori  = (const float*)d_in[4];
  const float* nw1 = (const float*)d_in[5];
  const float* nb1 = (const float*)d_in[6];
  const float* nw2 = (const float*)d_in[7];
  const float* nb2 = (const float*)d_in[8];
  const float* ew1 = (const float*)d_in[9];
  const float* eb1 = (const float*)d_in[10];
  const float* ew2 = (const float*)d_in[11];
  const float* eb2 = (const float*)d_in[12];
  const float* mw1 = (const float*)d_in[13];
  const float* mb1 = (const float*)d_in[14];
  const float* mw2 = (const float*)d_in[15];
  const float* mb2 = (const float*)d_in[16];
  const float* uw1 = (const float*)d_in[17];
  const float* ub1 = (const float*)d_in[18];
  const float* uw2 = (const float*)d_in[19];
  const float* ub2 = (const float*)d_in[20];

  int N = in_sizes[0] / 128;
  int G = in_sizes[2] / 3;
  int E = in_sizes[3] / 2;

  // ws layout kept within R1's proven footprint (~43 MB). The sorted-edge
  // buffer (E*8 = 8 MB) lives in d_out (G*128*4 = 16.8 MB), which is dead
  // until grid_kernel (last launch) — stream order makes the reuse safe.
  char* ws = (char*)d_ws;
  size_t off = 0;
  float* sums = (float*)(ws + off);            off += (size_t)G * 128 * 4;
  int* hist = (int*)(ws + off);                off += (size_t)G * 4;
  int* cursor = (int*)(ws + off);              off += (size_t)G * 4;
  unsigned short* node_pre = (unsigned short*)(ws + off); off += (size_t)N * 128 * 2;
  off = (off + 255) & ~(size_t)255;
  unsigned short* w_nw1t = (unsigned short*)(ws + off); off += 128 * 128 * 2;
  unsigned short* w_wnt  = (unsigned short*)(ws + off); off += 128 * 128 * 2;
  unsigned short* w_wct  = (unsigned short*)(ws + off); off += 128 * 128 * 2;
  unsigned short* w_mw2t = (unsigned short*)(ws + off); off += 128 * 128 * 2;
  unsigned short* w_uw1t = (unsigned short*)(ws + off); off += 128 * 128 * 2;
  unsigned short* w_uw2t = (unsigned short*)(ws + off); off += 128 * 128 * 2;
  float* bn = (float*)(ws + off); off += 128 * 4;
  float* bc = (float*)(ws + off); off += 128 * 4;

  int2* st_sorted = (int2*)d_out;   // scratch until grid_kernel overwrites it

  // zero sums + hist (contiguous)
  hipMemsetAsync(sums, 0, ((size_t)G * 128 + G) * 4, stream);

  fold_weights_kernel<<<128, 128, 0, stream>>>(nw1, nw2, nb2, ew2, eb2, mw1, mb1,
                                               mw2, uw1, uw2, w_nw1t, w_wnt, w_wct,
                                               w_mw2t, w_uw1t, w_uw2t, bn, bc);
  hist_kernel<<<(E + 511) / 512, 512, 0, stream>>>(eidx, hist, E);
  scan_kernel<<<1, 1024, 0, stream>>>(hist, cursor, G);
  scatter_kernel<<<(E + 511) / 512, 512, 0, stream>>>(eidx, cursor, st_sorted, E);
  node_kernel<<<(N + 255) / 256, 512, 0, stream>>>(x, nb1, w_nw1t, w_wnt, bn,
                                                   node_pre, N);
  edge_kernel<<<(E + 255) / 256, 512, 0, stream>>>(st_sorted, npos, gpos, ori, ew1,
                                                   eb1, w_wct, bc, node_pre, sums, E);
  grid_kernel<<<(G + 127) / 128, 256, 0, stream>>>(sums, hist, mb2, ub1, ub2,
                                                   w_mw2t, w_uw1t, w_uw2t,
                                                   (float*)d_out, G);
}

// Round 5
// 576.718 us; speedup vs baseline: 1.2618x; 1.1307x over previous
//
#include <hip/hip_runtime.h>

// LDS row pitch in ushorts: multiple of 8 (16B alignment for ds_read_b128),
// 136*2=272B -> dword stride 68 -> bank step 4 -> only 2-way aliasing (free).
#define P 136

typedef __attribute__((ext_vector_type(8))) short short8;
typedef __attribute__((ext_vector_type(4))) float f32x4;

__device__ __forceinline__ unsigned short f2bf(float f) {
  union { float f; unsigned u; } v; v.f = f;
  unsigned u = v.u + 0x7fffu + ((v.u >> 16) & 1u);   // RNE
  return (unsigned short)(u >> 16);
}
__device__ __forceinline__ float bf2f(unsigned short h) {
  union { unsigned u; float f; } v; v.u = ((unsigned)h) << 16;
  return v.f;
}
__device__ __forceinline__ float silu_f(float x) { return x / (1.0f + __expf(-x)); }

// One 2x8-tile (32 rows x 128 cols) MFMA GEMM over K=128.
__device__ __forceinline__ void gemm_32x128x128(const unsigned short* sA,
                                                const unsigned short* sB,
                                                int m0w, int q, int l16,
                                                f32x4 acc[2][8]) {
#pragma unroll
  for (int kt = 0; kt < 4; ++kt) {
    int ko = kt * 32 + q * 8;
    short8 a0 = *(const short8*)&sA[(m0w + l16) * P + ko];
    short8 a1 = *(const short8*)&sA[(m0w + 16 + l16) * P + ko];
#pragma unroll
    for (int ct = 0; ct < 8; ++ct) {
      short8 b = *(const short8*)&sB[(ct * 16 + l16) * P + ko];
      acc[0][ct] = __builtin_amdgcn_mfma_f32_16x16x32_bf16(a0, b, acc[0][ct], 0, 0, 0);
      acc[1][ct] = __builtin_amdgcn_mfma_f32_16x16x32_bf16(a1, b, acc[1][ct], 0, 0, 0);
    }
  }
}

// ---------------------------------------------------------------------------
// Weight folding:  Wn = nw2 @ mw1[:128], Wc = ew2 @ mw1[128:]
// Also emits ew1t8: ew1^T zero-padded K=6 -> 8  ([n][k], bf16).
// ---------------------------------------------------------------------------
__global__ void fold_weights_kernel(
    const float* __restrict__ nw1, const float* __restrict__ nw2,
    const float* __restrict__ nb2, const float* __restrict__ ew2,
    const float* __restrict__ eb2, const float* __restrict__ mw1,
    const float* __restrict__ mb1, const float* __restrict__ mw2,
    const float* __restrict__ uw1, const float* __restrict__ uw2,
    const float* __restrict__ ew1,
    unsigned short* __restrict__ nw1t, unsigned short* __restrict__ wnt,
    unsigned short* __restrict__ wct, unsigned short* __restrict__ mw2t,
    unsigned short* __restrict__ uw1t, unsigned short* __restrict__ uw2t,
    unsigned short* __restrict__ ew1t8,
    float* __restrict__ bn, float* __restrict__ bc) {
  int b = blockIdx.x;   // n (output col)
  int t = threadIdx.x;  // k (input row)
  float accn = 0.f, accc = 0.f;
  for (int j = 0; j < 128; ++j) {
    accn += nw2[t * 128 + j] * mw1[j * 128 + b];
    accc += ew2[t * 128 + j] * mw1[(128 + j) * 128 + b];
  }
  wnt[b * 128 + t] = f2bf(accn);
  wct[b * 128 + t] = f2bf(accc);
  nw1t[b * 128 + t] = f2bf(nw1[t * 128 + b]);
  mw2t[b * 128 + t] = f2bf(mw2[t * 128 + b]);
  uw1t[b * 128 + t] = f2bf(uw1[t * 128 + b]);
  uw2t[b * 128 + t] = f2bf(uw2[t * 128 + b]);
  if (t < 8) ew1t8[b * 8 + t] = (t < 6) ? f2bf(ew1[t * 128 + b]) : (unsigned short)0;
  if (b == 0) {
    float sn = 0.f, sc = 0.f;
    for (int j = 0; j < 128; ++j) {
      sn += nb2[j] * mw1[j * 128 + t];
      sc += eb2[j] * mw1[(128 + j) * 128 + t];
    }
    bn[t] = sn;
    bc[t] = mb1[t] + sc;
  }
}

// ---------------------------------------------------------------------------
// Sort scaffolding: histogram of tgt, prefix scan, scatter of (src,tgt).
// ---------------------------------------------------------------------------
__global__ void hist_kernel(const int* __restrict__ eidx, int* __restrict__ hist,
                            int E) {
  int e = blockIdx.x * blockDim.x + threadIdx.x;
  if (e < E) atomicAdd(&hist[eidx[E + e]], 1);
}

__global__ __launch_bounds__(1024) void scan_kernel(const int* __restrict__ hist,
                                                    int* __restrict__ cursor, int G) {
  __shared__ int s[1024];
  int tid = threadIdx.x;
  int per = (G + 1023) >> 10;
  int b0 = tid * per;
  int sum = 0;
  for (int i = 0; i < per; ++i)
    if (b0 + i < G) sum += hist[b0 + i];
  s[tid] = sum;
  __syncthreads();
  for (int off = 1; off < 1024; off <<= 1) {
    int v = (tid >= off) ? s[tid - off] : 0;
    __syncthreads();
    s[tid] += v;
    __syncthreads();
  }
  int run = s[tid] - sum;  // exclusive prefix
  for (int i = 0; i < per; ++i)
    if (b0 + i < G) {
      cursor[b0 + i] = run;
      run += hist[b0 + i];
    }
}

__global__ void scatter_kernel(const int* __restrict__ eidx, int* __restrict__ cursor,
                               int2* __restrict__ st, int E) {
  int e = blockIdx.x * blockDim.x + threadIdx.x;
  if (e < E) {
    int tg = eidx[E + e];
    int pos = atomicAdd(&cursor[tg], 1);
    st[pos] = make_int2(eidx[e], tg);
  }
}

// ---------------------------------------------------------------------------
// Node kernel: node_pre = (silu(x@nw1 + nb1)) @ Wn + bn   -> bf16 [N,128]
// 128 rows / 256 threads / 4 waves; ~70 KB LDS -> 2 blocks/CU.
// ---------------------------------------------------------------------------
__global__ __launch_bounds__(256, 2) void node_kernel(
    const float* __restrict__ x, const float* __restrict__ nb1,
    const unsigned short* __restrict__ nw1t, const unsigned short* __restrict__ wnt,
    const float* __restrict__ bn, unsigned short* __restrict__ node_pre, int N) {
  __shared__ __align__(16) unsigned short s_w[128 * P];
  __shared__ __align__(16) unsigned short s_x[128 * P];
  __shared__ float s_b1[128];
  __shared__ float s_bn[128];
  int tid = threadIdx.x;
  long base = (long)blockIdx.x * 128;

#pragma unroll
  for (int i = 0; i < 16; ++i) {
    int flat = tid + i * 256;      // 4096 float4 = 128 rows x 32
    int row = flat >> 5;
    int c4 = (flat & 31) << 2;
    float4 v = make_float4(0.f, 0.f, 0.f, 0.f);
    if (base + row < N) v = *(const float4*)&x[(base + row) * 128 + c4];
    unsigned p0 = (unsigned)f2bf(v.x) | ((unsigned)f2bf(v.y) << 16);
    unsigned p1 = (unsigned)f2bf(v.z) | ((unsigned)f2bf(v.w) << 16);
    *(uint2*)&s_x[row * P + c4] = make_uint2(p0, p1);
  }
#pragma unroll
  for (int i = 0; i < 8; ++i) {
    int ch = tid + i * 256;
    int r = ch >> 4, c8 = (ch & 15) << 3;
    *(short8*)&s_w[r * P + c8] = *(const short8*)&nw1t[r * 128 + c8];
  }
  if (tid < 128) { s_b1[tid] = nb1[tid]; s_bn[tid] = bn[tid]; }
  __syncthreads();

  int wave = tid >> 6, lane = tid & 63;
  int q = lane >> 4, l16 = lane & 15;
  int m0w = wave * 32;

  f32x4 acc[2][8];
#pragma unroll
  for (int rt = 0; rt < 2; ++rt)
#pragma unroll
    for (int ct = 0; ct < 8; ++ct) acc[rt][ct] = (f32x4){0.f, 0.f, 0.f, 0.f};
  gemm_32x128x128(s_x, s_w, m0w, q, l16, acc);
  __syncthreads();

#pragma unroll
  for (int rt = 0; rt < 2; ++rt)
#pragma unroll
    for (int r = 0; r < 4; ++r) {
      int m = m0w + rt * 16 + q * 4 + r;
#pragma unroll
      for (int ct = 0; ct < 8; ++ct) {
        int n = ct * 16 + l16;
        s_x[m * P + n] = f2bf(silu_f(acc[rt][ct][r] + s_b1[n]));
      }
    }
#pragma unroll
  for (int i = 0; i < 8; ++i) {
    int ch = tid + i * 256;
    int r = ch >> 4, c8 = (ch & 15) << 3;
    *(short8*)&s_w[r * P + c8] = *(const short8*)&wnt[r * 128 + c8];
  }
  __syncthreads();

  f32x4 acc2[2][8];
#pragma unroll
  for (int rt = 0; rt < 2; ++rt)
#pragma unroll
    for (int ct = 0; ct < 8; ++ct) acc2[rt][ct] = (f32x4){0.f, 0.f, 0.f, 0.f};
  gemm_32x128x128(s_x, s_w, m0w, q, l16, acc2);

#pragma unroll
  for (int rt = 0; rt < 2; ++rt)
#pragma unroll
    for (int r = 0; r < 4; ++r) {
      int m = m0w + rt * 16 + q * 4 + r;
      if (base + m < N) {
#pragma unroll
        for (int ct = 0; ct < 8; ++ct) {
          int n = ct * 16 + l16;
          node_pre[(base + m) * 128 + n] = f2bf(acc2[rt][ct][r] + s_bn[n]);
        }
      }
    }
}

// ---------------------------------------------------------------------------
// Edge kernel (sorted edges), 128 edges / 256 threads / 4 waves, 2 blocks/CU.
//   attr (K=8, masked to q==0 lanes) --MFMA--> h1=silu(.+eb1)
//   h1 @ Wc  (+ node_pre[src] injected via identity-B MFMA)  + bc --silu--> h2
//   segmented reduction over tgt runs -> atomicAdd into sums (h2-space)
// mw2 applied later in grid_kernel (linearity of mean).
// ---------------------------------------------------------------------------
__global__ __launch_bounds__(256, 2) void edge_kernel(
    const int2* __restrict__ st_sorted, const float* __restrict__ node_pos,
    const float* __restrict__ grid_pos, const float* __restrict__ ori,
    const unsigned short* __restrict__ ew1t8, const float* __restrict__ eb1,
    const unsigned short* __restrict__ wct, const float* __restrict__ bc,
    const unsigned short* __restrict__ node_pre, float* __restrict__ sums, int E) {
  __shared__ __align__(16) unsigned short s_wc[128 * P];
  __shared__ __align__(16) unsigned short s_h[128 * P];
  __shared__ __align__(16) unsigned short s_e1[128 * 8];   // ew1^T K=8, 2 KB
  __shared__ int s_src[128];
  __shared__ int s_tgt[128];
  __shared__ float s_eb1[128];
  __shared__ float s_bc[128];

  int tid = threadIdx.x;
  int base = blockIdx.x * 128;

#pragma unroll
  for (int i = 0; i < 8; ++i) {
    int ch = tid + i * 256;
    int r = ch >> 4, c8 = (ch & 15) << 3;
    *(short8*)&s_wc[r * P + c8] = *(const short8*)&wct[r * 128 + c8];
  }
  if (tid < 128) {
    *(uint4*)&s_e1[tid * 8] = *(const uint4*)&ew1t8[tid * 8];
    s_eb1[tid] = eb1[tid];
    s_bc[tid] = bc[tid];
    // per-edge geometry -> attr (6 vals + 2 pad) into s_h cols [0,8)
    int eg = base + tid;
    int s = 0, tg = -1;
    float a0 = 0.f, a1 = 0.f, a2 = 0.f, a3 = 0.f, a4 = 0.f, a5 = 0.f;
    if (eg < E) {
      int2 st = st_sorted[eg];
      s = st.x; tg = st.y;
      float px = node_pos[s * 3 + 0], py = node_pos[s * 3 + 1], pz = node_pos[s * 3 + 2];
      float rx = grid_pos[tg * 3 + 0] - px;
      float ry = grid_pos[tg * 3 + 1] - py;
      float rz = grid_pos[tg * 3 + 2] - pz;
      const float* o = &ori[(long)s * 9];
      a0 = px; a1 = py; a2 = pz;
      a3 = rx * o[0] + ry * o[3] + rz * o[6];
      a4 = rx * o[1] + ry * o[4] + rz * o[7];
      a5 = rx * o[2] + ry * o[5] + rz * o[8];
    }
    s_src[tid] = s;
    s_tgt[tid] = tg;
    uint4 w0;
    w0.x = (unsigned)f2bf(a0) | ((unsigned)f2bf(a1) << 16);
    w0.y = (unsigned)f2bf(a2) | ((unsigned)f2bf(a3) << 16);
    w0.z = (unsigned)f2bf(a4) | ((unsigned)f2bf(a5) << 16);
    w0.w = 0u;
    *(uint4*)&s_h[tid * P] = w0;
  }
  __syncthreads();

  int wave = tid >> 6, lane = tid & 63;
  int q = lane >> 4, l16 = lane & 15;
  int m0w = wave * 32;

  // Early gather: node_pre rows in A-fragment layout (16B vector loads).
  long sr0 = (long)s_src[m0w + l16] * 128 + q * 8;
  long sr1 = (long)s_src[m0w + 16 + l16] * 128 + q * 8;
  short8 anp0[4], anp1[4];
#pragma unroll
  for (int kt = 0; kt < 4; ++kt) {
    anp0[kt] = *(const short8*)&node_pre[sr0 + kt * 32];
    anp1[kt] = *(const short8*)&node_pre[sr1 + kt * 32];
  }

  // Identity B fragments for the injection MFMAs (bf16 1.0 = 0x3F80).
  short8 bI0, bI1;
#pragma unroll
  for (int j = 0; j < 8; ++j) {
    int k = q * 8 + j;
    bI0[j] = (k == l16) ? (short)0x3F80 : (short)0;
    bI1[j] = (k == l16 + 16) ? (short)0x3F80 : (short)0;
  }

  short8 z8;
#pragma unroll
  for (int j = 0; j < 8; ++j) z8[j] = 0;

  // GEMM0: attr(K=8, q==0 lanes only) @ ew1 -> h1 pre-act
  f32x4 acc[2][8];
#pragma unroll
  for (int rt = 0; rt < 2; ++rt)
#pragma unroll
    for (int ct = 0; ct < 8; ++ct) acc[rt][ct] = (f32x4){0.f, 0.f, 0.f, 0.f};
  {
    short8 a0 = z8, a1 = z8;
    if (q == 0) {
      a0 = *(const short8*)&s_h[(m0w + l16) * P];
      a1 = *(const short8*)&s_h[(m0w + 16 + l16) * P];
    }
#pragma unroll
    for (int ct = 0; ct < 8; ++ct) {
      short8 b = z8;
      if (q == 0) b = *(const short8*)&s_e1[(ct * 16 + l16) * 8];
      acc[0][ct] = __builtin_amdgcn_mfma_f32_16x16x32_bf16(a0, b, acc[0][ct], 0, 0, 0);
      acc[1][ct] = __builtin_amdgcn_mfma_f32_16x16x32_bf16(a1, b, acc[1][ct], 0, 0, 0);
    }
  }
  __syncthreads();  // GEMM0 reads of s_h done before overwrite

  // h1 = silu(acc + eb1) -> s_h
#pragma unroll
  for (int rt = 0; rt < 2; ++rt)
#pragma unroll
    for (int r = 0; r < 4; ++r) {
      int m = m0w + rt * 16 + q * 4 + r;
#pragma unroll
      for (int ct = 0; ct < 8; ++ct) {
        int n = ct * 16 + l16;
        s_h[m * P + n] = f2bf(silu_f(acc[rt][ct][r] + s_eb1[n]));
      }
    }
  __syncthreads();

  // GEMM1: h1 @ Wc
#pragma unroll
  for (int rt = 0; rt < 2; ++rt)
#pragma unroll
    for (int ct = 0; ct < 8; ++ct) acc[rt][ct] = (f32x4){0.f, 0.f, 0.f, 0.f};
  gemm_32x128x128(s_h, s_wc, m0w, q, l16, acc);

  // inject node_pre[src]: D += A_np * I  (16 MFMAs, no scalar gather)
#pragma unroll
  for (int kt = 0; kt < 4; ++kt) {
    acc[0][2 * kt]     = __builtin_amdgcn_mfma_f32_16x16x32_bf16(anp0[kt], bI0, acc[0][2 * kt], 0, 0, 0);
    acc[0][2 * kt + 1] = __builtin_amdgcn_mfma_f32_16x16x32_bf16(anp0[kt], bI1, acc[0][2 * kt + 1], 0, 0, 0);
    acc[1][2 * kt]     = __builtin_amdgcn_mfma_f32_16x16x32_bf16(anp1[kt], bI0, acc[1][2 * kt], 0, 0, 0);
    acc[1][2 * kt + 1] = __builtin_amdgcn_mfma_f32_16x16x32_bf16(anp1[kt], bI1, acc[1][2 * kt + 1], 0, 0, 0);
  }
  __syncthreads();  // GEMM1 reads of s_h done

  // h2 = silu(acc + bc) -> s_h
#pragma unroll
  for (int rt = 0; rt < 2; ++rt)
#pragma unroll
    for (int r = 0; r < 4; ++r) {
      int m = m0w + rt * 16 + q * 4 + r;
#pragma unroll
      for (int ct = 0; ct < 8; ++ct) {
        int n = ct * 16 + l16;
        s_h[m * P + n] = f2bf(silu_f(acc[rt][ct][r] + s_bc[n]));
      }
    }
  __syncthreads();

  // segmented reduction: thread = (colpair, 32-row chunk); flush per run.
  {
    int cp = tid & 63;
    int chunk = tid >> 6;       // 4 chunks x 32 rows
    int c0 = cp * 2;
    int row0 = chunk * 32;
    float v0 = 0.f, v1 = 0.f;
    int cur = s_tgt[row0];
    for (int r = 0; r < 32; ++r) {
      int row = row0 + r;
      int tg = s_tgt[row];
      if (tg != cur) {
        if (cur >= 0) {
          atomicAdd(&sums[(long)cur * 128 + c0], v0);
          atomicAdd(&sums[(long)cur * 128 + c0 + 1], v1);
        }
        v0 = 0.f; v1 = 0.f; cur = tg;
      }
      unsigned w = *(const unsigned*)&s_h[row * P + c0];
      v0 += bf2f((unsigned short)w);
      v1 += bf2f((unsigned short)(w >> 16));
    }
    if (cur >= 0) {
      atomicAdd(&sums[(long)cur * 128 + c0], v0);
      atomicAdd(&sums[(long)cur * 128 + c0 + 1], v1);
    }
  }
}

// ---------------------------------------------------------------------------
// Grid kernel: x = sums/clip(hist,1);  y = x@mw2 + mb2 (grid_feat);
//              out = silu(y@uw1+ub1)@uw2 + ub2
// ---------------------------------------------------------------------------
__global__ __launch_bounds__(256, 2) void grid_kernel(
    const float* __restrict__ sums, const int* __restrict__ hist,
    const float* __restrict__ mb2, const float* __restrict__ ub1,
    const float* __restrict__ ub2, const unsigned short* __restrict__ mw2t,
    const unsigned short* __restrict__ uw1t, const unsigned short* __restrict__ uw2t,
    float* __restrict__ out, int G) {
  __shared__ __align__(16) unsigned short s_w[128 * P];
  __shared__ __align__(16) unsigned short s_x[128 * P];
  __shared__ float s_bm[128];
  __shared__ float s_b1[128];
  __shared__ float s_b2[128];
  int tid = threadIdx.x;
  long base = (long)blockIdx.x * 128;

#pragma unroll
  for (int i = 0; i < 16; ++i) {
    int flat = tid + i * 256;       // 4096 float4 = 128 rows x 32
    int row = flat >> 5;
    int c4 = (flat & 31) << 2;
    float4 v = make_float4(0.f, 0.f, 0.f, 0.f);
    float inv = 1.f;
    if (base + row < G) {
      v = *(const float4*)&sums[(base + row) * 128 + c4];
      int c = hist[base + row];
      inv = 1.f / (float)(c < 1 ? 1 : c);
    }
    unsigned p0 = (unsigned)f2bf(v.x * inv) | ((unsigned)f2bf(v.y * inv) << 16);
    unsigned p1 = (unsigned)f2bf(v.z * inv) | ((unsigned)f2bf(v.w * inv) << 16);
    *(uint2*)&s_x[row * P + c4] = make_uint2(p0, p1);
  }
#pragma unroll
  for (int i = 0; i < 8; ++i) {
    int ch = tid + i * 256;
    int r = ch >> 4, c8 = (ch & 15) << 3;
    *(short8*)&s_w[r * P + c8] = *(const short8*)&mw2t[r * 128 + c8];
  }
  if (tid < 128) { s_bm[tid] = mb2[tid]; s_b1[tid] = ub1[tid]; s_b2[tid] = ub2[tid]; }
  __syncthreads();

  int wave = tid >> 6, lane = tid & 63;
  int q = lane >> 4, l16 = lane & 15;
  int m0w = wave * 32;

  // GEMM A: grid_feat = x@mw2 + mb2  (no activation)
  f32x4 acc[2][8];
#pragma unroll
  for (int rt = 0; rt < 2; ++rt)
#pragma unroll
    for (int ct = 0; ct < 8; ++ct) acc[rt][ct] = (f32x4){0.f, 0.f, 0.f, 0.f};
  gemm_32x128x128(s_x, s_w, m0w, q, l16, acc);
  __syncthreads();
#pragma unroll
  for (int rt = 0; rt < 2; ++rt)
#pragma unroll
    for (int r = 0; r < 4; ++r) {
      int m = m0w + rt * 16 + q * 4 + r;
#pragma unroll
      for (int ct = 0; ct < 8; ++ct) {
        int n = ct * 16 + l16;
        s_x[m * P + n] = f2bf(acc[rt][ct][r] + s_bm[n]);
      }
    }
#pragma unroll
  for (int i = 0; i < 8; ++i) {
    int ch = tid + i * 256;
    int r = ch >> 4, c8 = (ch & 15) << 3;
    *(short8*)&s_w[r * P + c8] = *(const short8*)&uw1t[r * 128 + c8];
  }
  __syncthreads();

  // GEMM B: silu(y@uw1 + ub1)
#pragma unroll
  for (int rt = 0; rt < 2; ++rt)
#pragma unroll
    for (int ct = 0; ct < 8; ++ct) acc[rt][ct] = (f32x4){0.f, 0.f, 0.f, 0.f};
  gemm_32x128x128(s_x, s_w, m0w, q, l16, acc);
  __syncthreads();
#pragma unroll
  for (int rt = 0; rt < 2; ++rt)
#pragma unroll
    for (int r = 0; r < 4; ++r) {
      int m = m0w + rt * 16 + q * 4 + r;
#pragma unroll
      for (int ct = 0; ct < 8; ++ct) {
        int n = ct * 16 + l16;
        s_x[m * P + n] = f2bf(silu_f(acc[rt][ct][r] + s_b1[n]));
      }
    }
#pragma unroll
  for (int i = 0; i < 8; ++i) {
    int ch = tid + i * 256;
    int r = ch >> 4, c8 = (ch & 15) << 3;
    *(short8*)&s_w[r * P + c8] = *(const short8*)&uw2t[r * 128 + c8];
  }
  __syncthreads();

  // GEMM C: out = h@uw2 + ub2
#pragma unroll
  for (int rt = 0; rt < 2; ++rt)
#pragma unroll
    for (int ct = 0; ct < 8; ++ct) acc[rt][ct] = (f32x4){0.f, 0.f, 0.f, 0.f};
  gemm_32x128x128(s_x, s_w, m0w, q, l16, acc);

#pragma unroll
  for (int rt = 0; rt < 2; ++rt)
#pragma unroll
    for (int r = 0; r < 4; ++r) {
      int m = m0w + rt * 16 + q * 4 + r;
      if (base + m < G) {
#pragma unroll
        for (int ct = 0; ct < 8; ++ct) {
          int n = ct * 16 + l16;
          out[(base + m) * 128 + n] = acc[rt][ct][r] + s_b2[n];
        }
      }
    }
}

extern "C" void kernel_launch(void* const* d_in, const int* in_sizes, int n_in,
                              void* d_out, int out_size, void* d_ws, size_t ws_size,
                              hipStream_t stream) {
  const float* x    = (const float*)d_in[0];
  const float* npos = (const float*)d_in[1];
  const float* gpos = (const float*)d_in[2];
  const int*   eidx = (const int*)d_in[3];
  const float* ori  = (const float*)d_in[4];
  const float* nw1 = (const float*)d_in[5];
  const float* nb1 = (const float*)d_in[6];
  const float* nw2 = (const float*)d_in[7];
  const float* nb2 = (const float*)d_in[8];
  const float* ew1 = (const float*)d_in[9];
  const float* eb1 = (const float*)d_in[10];
  const float* ew2 = (const float*)d_in[11];
  const float* eb2 = (const float*)d_in[12];
  const float* mw1 = (const float*)d_in[13];
  const float* mb1 = (const float*)d_in[14];
  const float* mw2 = (const float*)d_in[15];
  const float* mb2 = (const float*)d_in[16];
  const float* uw1 = (const float*)d_in[17];
  const float* ub1 = (const float*)d_in[18];
  const float* uw2 = (const float*)d_in[19];
  const float* ub2 = (const float*)d_in[20];

  int N = in_sizes[0] / 128;
  int G = in_sizes[2] / 3;
  int E = in_sizes[3] / 2;

  // ws layout kept within R1's proven footprint (~43 MB). The sorted-edge
  // buffer (E*8 = 8 MB) lives in d_out (G*128*4 = 16.8 MB), which is dead
  // until grid_kernel (last launch) — stream order makes the reuse safe.
  char* ws = (char*)d_ws;
  size_t off = 0;
  float* sums = (float*)(ws + off);            off += (size_t)G * 128 * 4;
  int* hist = (int*)(ws + off);                off += (size_t)G * 4;
  int* cursor = (int*)(ws + off);              off += (size_t)G * 4;
  unsigned short* node_pre = (unsigned short*)(ws + off); off += (size_t)N * 128 * 2;
  off = (off + 255) & ~(size_t)255;
  unsigned short* w_nw1t = (unsigned short*)(ws + off); off += 128 * 128 * 2;
  unsigned short* w_wnt  = (unsigned short*)(ws + off); off += 128 * 128 * 2;
  unsigned short* w_wct  = (unsigned short*)(ws + off); off += 128 * 128 * 2;
  unsigned short* w_mw2t = (unsigned short*)(ws + off); off += 128 * 128 * 2;
  unsigned short* w_uw1t = (unsigned short*)(ws + off); off += 128 * 128 * 2;
  unsigned short* w_uw2t = (unsigned short*)(ws + off); off += 128 * 128 * 2;
  unsigned short* w_ew1t8 = (unsigned short*)(ws + off); off += 128 * 8 * 2;
  float* bn = (float*)(ws + off); off += 128 * 4;
  float* bc = (float*)(ws + off); off += 128 * 4;

  int2* st_sorted = (int2*)d_out;   // scratch until grid_kernel overwrites it

  // zero sums + hist (contiguous)
  hipMemsetAsync(sums, 0, ((size_t)G * 128 + G) * 4, stream);

  fold_weights_kernel<<<128, 128, 0, stream>>>(nw1, nw2, nb2, ew2, eb2, mw1, mb1,
                                               mw2, uw1, uw2, ew1, w_nw1t, w_wnt,
                                               w_wct, w_mw2t, w_uw1t, w_uw2t,
                                               w_ew1t8, bn, bc);
  hist_kernel<<<(E + 511) / 512, 512, 0, stream>>>(eidx, hist, E);
  scan_kernel<<<1, 1024, 0, stream>>>(hist, cursor, G);
  scatter_kernel<<<(E + 511) / 512, 512, 0, stream>>>(eidx, cursor, st_sorted, E);
  node_kernel<<<(N + 127) / 128, 256, 0, stream>>>(x, nb1, w_nw1t, w_wnt, bn,
                                                   node_pre, N);
  edge_kernel<<<(E + 127) / 128, 256, 0, stream>>>(st_sorted, npos, gpos, ori,
                                                   w_ew1t8, eb1, w_wct, bc,
                                                   node_pre, sums, E);
  grid_kernel<<<(G + 127) / 128, 256, 0, stream>>>(sums, hist, mb2, ub1, ub2,
                                                   w_mw2t, w_uw1t, w_uw2t,
                                                   (float*)d_out, G);
}

// Round 7
// 551.693 us; speedup vs baseline: 1.3190x; 1.0454x over previous
//
#include <hip/hip_runtime.h>

// LDS row pitch in ushorts: 136*2=272B -> dword stride 68 -> bank step 4 ->
// only 2-way aliasing (free). 272 is a multiple of 16 -> rows stay 16B-aligned.
#define P 136

typedef __attribute__((ext_vector_type(8))) short short8;
typedef __attribute__((ext_vector_type(4))) float f32x4;

__device__ __forceinline__ unsigned short f2bf(float f) {
  union { float f; unsigned u; } v; v.f = f;
  unsigned u = v.u + 0x7fffu + ((v.u >> 16) & 1u);   // RNE
  return (unsigned short)(u >> 16);
}
__device__ __forceinline__ float bf2f(unsigned short h) {
  union { unsigned u; float f; } v; v.u = ((unsigned)h) << 16;
  return v.f;
}
// pack two floats -> bf16x2 dword (RNE both)
__device__ __forceinline__ unsigned pack2bf(float x, float y) {
  union { float f; unsigned u; } a, b; a.f = x; b.f = y;
  unsigned lo = (a.u + 0x7fffu + ((a.u >> 16) & 1u)) >> 16;
  unsigned hi = (b.u + 0x7fffu + ((b.u >> 16) & 1u)) & 0xffff0000u;
  return lo | hi;
}
__device__ __forceinline__ float silu_f(float x) { return x / (1.0f + __expf(-x)); }

// Transposed-GEMM building blocks. D[m=feat][n=row]:
//   A = W^T [feat][k] in REGISTERS (8 x short8 per wave, rows m0w..m0w+31)
//   B = X   [row][k]  in LDS, pitch P (contiguous b128 reads)
// C/D: lane holds n(row)=l16 (per ct tile), m(feat)=m0w+rt*16+q*4+r -> 4
// consecutive feature cols per lane => packed 8B epilogue stores.
__device__ __forceinline__ void load_A128(const unsigned short* __restrict__ W,
                                          int m0w, int l16, int q, short8 a[2][4]) {
#pragma unroll
  for (int rt = 0; rt < 2; ++rt)
#pragma unroll
    for (int kt = 0; kt < 4; ++kt)
      a[rt][kt] = *(const short8*)&W[(m0w + rt * 16 + l16) * 128 + kt * 32 + q * 8];
}

__device__ __forceinline__ void gemm_T(const short8 a[2][4],
                                       const unsigned short* sB,
                                       int l16, int q, f32x4 acc[2][8]) {
#pragma unroll
  for (int kt = 0; kt < 4; ++kt)
#pragma unroll
    for (int ct = 0; ct < 8; ++ct) {
      short8 b = *(const short8*)&sB[(ct * 16 + l16) * P + kt * 32 + q * 8];
      acc[0][ct] = __builtin_amdgcn_mfma_f32_16x16x32_bf16(a[0][kt], b, acc[0][ct], 0, 0, 0);
      acc[1][ct] = __builtin_amdgcn_mfma_f32_16x16x32_bf16(a[1][kt], b, acc[1][ct], 0, 0, 0);
    }
}

template <bool SILU>
__device__ __forceinline__ void epilogue_T(const f32x4 acc[2][8], const float* bias,
                                           unsigned short* sOut, int m0w, int l16,
                                           int q) {
#pragma unroll
  for (int rt = 0; rt < 2; ++rt) {
    int f0 = m0w + rt * 16 + q * 4;
    float b0 = bias[f0], b1 = bias[f0 + 1], b2 = bias[f0 + 2], b3 = bias[f0 + 3];
#pragma unroll
    for (int ct = 0; ct < 8; ++ct) {
      float v0 = acc[rt][ct][0] + b0, v1 = acc[rt][ct][1] + b1;
      float v2 = acc[rt][ct][2] + b2, v3 = acc[rt][ct][3] + b3;
      if (SILU) { v0 = silu_f(v0); v1 = silu_f(v1); v2 = silu_f(v2); v3 = silu_f(v3); }
      uint2 w; w.x = pack2bf(v0, v1); w.y = pack2bf(v2, v3);
      *(uint2*)&sOut[(ct * 16 + l16) * P + f0] = w;
    }
  }
}

// ---------------------------------------------------------------------------
// Weight folding:  Wn = nw2 @ mw1[:128], Wc = ew2 @ mw1[128:]
// All large matrices stored TRANSPOSED [n][k] bf16 (A-operand layout).
// ---------------------------------------------------------------------------
__global__ void fold_weights_kernel(
    const float* __restrict__ nw1, const float* __restrict__ nw2,
    const float* __restrict__ nb2, const float* __restrict__ ew2,
    const float* __restrict__ eb2, const float* __restrict__ mw1,
    const float* __restrict__ mb1, const float* __restrict__ mw2,
    const float* __restrict__ uw1, const float* __restrict__ uw2,
    const float* __restrict__ ew1,
    unsigned short* __restrict__ nw1t, unsigned short* __restrict__ wnt,
    unsigned short* __restrict__ wct, unsigned short* __restrict__ mw2t,
    unsigned short* __restrict__ uw1t, unsigned short* __restrict__ uw2t,
    unsigned short* __restrict__ ew1t8,
    float* __restrict__ bn, float* __restrict__ bc) {
  int b = blockIdx.x;   // n (output col)
  int t = threadIdx.x;  // k (input row)
  float accn = 0.f, accc = 0.f;
  for (int j = 0; j < 128; ++j) {
    accn += nw2[t * 128 + j] * mw1[j * 128 + b];
    accc += ew2[t * 128 + j] * mw1[(128 + j) * 128 + b];
  }
  wnt[b * 128 + t] = f2bf(accn);
  wct[b * 128 + t] = f2bf(accc);
  nw1t[b * 128 + t] = f2bf(nw1[t * 128 + b]);
  mw2t[b * 128 + t] = f2bf(mw2[t * 128 + b]);
  uw1t[b * 128 + t] = f2bf(uw1[t * 128 + b]);
  uw2t[b * 128 + t] = f2bf(uw2[t * 128 + b]);
  if (t < 8) ew1t8[b * 8 + t] = (t < 6) ? f2bf(ew1[t * 128 + b]) : (unsigned short)0;
  if (b == 0) {
    float sn = 0.f, sc = 0.f;
    for (int j = 0; j < 128; ++j) {
      sn += nb2[j] * mw1[j * 128 + t];
      sc += eb2[j] * mw1[(128 + j) * 128 + t];
    }
    bn[t] = sn;
    bc[t] = mb1[t] + sc;
  }
}

// ---------------------------------------------------------------------------
// Sort scaffolding: histogram of tgt, prefix scan, scatter of (src,tgt).
// ---------------------------------------------------------------------------
__global__ void hist_kernel(const int* __restrict__ eidx, int* __restrict__ hist,
                            int E) {
  int e = blockIdx.x * blockDim.x + threadIdx.x;
  if (e < E) atomicAdd(&hist[eidx[E + e]], 1);
}

__global__ __launch_bounds__(1024) void scan_kernel(const int* __restrict__ hist,
                                                    int* __restrict__ cursor, int G) {
  __shared__ int s[1024];
  int tid = threadIdx.x;
  int per = (G + 1023) >> 10;
  int b0 = tid * per;
  int sum = 0;
  for (int i = 0; i < per; ++i)
    if (b0 + i < G) sum += hist[b0 + i];
  s[tid] = sum;
  __syncthreads();
  for (int off = 1; off < 1024; off <<= 1) {
    int v = (tid >= off) ? s[tid - off] : 0;
    __syncthreads();
    s[tid] += v;
    __syncthreads();
  }
  int run = s[tid] - sum;  // exclusive prefix
  for (int i = 0; i < per; ++i)
    if (b0 + i < G) {
      cursor[b0 + i] = run;
      run += hist[b0 + i];
    }
}

__global__ void scatter_kernel(const int* __restrict__ eidx, int* __restrict__ cursor,
                               int2* __restrict__ st, int E) {
  int e = blockIdx.x * blockDim.x + threadIdx.x;
  if (e < E) {
    int tg = eidx[E + e];
    int pos = atomicAdd(&cursor[tg], 1);
    st[pos] = make_int2(eidx[e], tg);
  }
}

// ---------------------------------------------------------------------------
// Node kernel (transposed): node_pre = silu(x@nw1+nb1) @ Wn + bn -> bf16 [N,128]
// 128 rows / 256 threads; LDS ~36 KB; weights in registers.
// ---------------------------------------------------------------------------
__global__ __launch_bounds__(256, 3) void node_kernel(
    const float* __restrict__ x, const float* __restrict__ nb1,
    const unsigned short* __restrict__ nw1t, const unsigned short* __restrict__ wnt,
    const float* __restrict__ bn, unsigned short* __restrict__ node_pre, int N) {
  __shared__ __align__(16) unsigned short s_x[128 * P];
  __shared__ float s_b1[128];
  __shared__ float s_bn[128];
  int tid = threadIdx.x;
  long base = (long)blockIdx.x * 128;

#pragma unroll
  for (int i = 0; i < 16; ++i) {
    int flat = tid + i * 256;      // 4096 float4 = 128 rows x 32
    int row = flat >> 5;
    int c4 = (flat & 31) << 2;
    float4 v = make_float4(0.f, 0.f, 0.f, 0.f);
    if (base + row < N) v = *(const float4*)&x[(base + row) * 128 + c4];
    uint2 w; w.x = pack2bf(v.x, v.y); w.y = pack2bf(v.z, v.w);
    *(uint2*)&s_x[row * P + c4] = w;
  }
  if (tid < 128) { s_b1[tid] = nb1[tid]; s_bn[tid] = bn[tid]; }
  __syncthreads();

  int wave = tid >> 6, lane = tid & 63;
  int q = lane >> 4, l16 = lane & 15;
  int m0w = wave * 32;

  short8 a1[2][4];
  load_A128(nw1t, m0w, l16, q, a1);
  f32x4 acc[2][8];
#pragma unroll
  for (int rt = 0; rt < 2; ++rt)
#pragma unroll
    for (int ct = 0; ct < 8; ++ct) acc[rt][ct] = (f32x4){0.f, 0.f, 0.f, 0.f};
  gemm_T(a1, s_x, l16, q, acc);
  __syncthreads();
  epilogue_T<true>(acc, s_b1, s_x, m0w, l16, q);
  __syncthreads();

  short8 a2[2][4];
  load_A128(wnt, m0w, l16, q, a2);
#pragma unroll
  for (int rt = 0; rt < 2; ++rt)
#pragma unroll
    for (int ct = 0; ct < 8; ++ct) acc[rt][ct] = (f32x4){0.f, 0.f, 0.f, 0.f};
  gemm_T(a2, s_x, l16, q, acc);

  // store node_pre[node][feat] packed 8B
#pragma unroll
  for (int rt = 0; rt < 2; ++rt) {
    int f0 = m0w + rt * 16 + q * 4;
    float b0 = s_bn[f0], b1 = s_bn[f0 + 1], b2 = s_bn[f0 + 2], b3 = s_bn[f0 + 3];
#pragma unroll
    for (int ct = 0; ct < 8; ++ct) {
      long n = base + ct * 16 + l16;
      if (n < N) {
        uint2 w;
        w.x = pack2bf(acc[rt][ct][0] + b0, acc[rt][ct][1] + b1);
        w.y = pack2bf(acc[rt][ct][2] + b2, acc[rt][ct][3] + b3);
        *(uint2*)&node_pre[n * 128 + f0] = w;
      }
    }
  }
}

// ---------------------------------------------------------------------------
// Edge kernel (sorted edges, transposed GEMMs), 128 edges / 256 threads.
//   attr(K=8) --MFMA--> h1 = silu(.+eb1)        (ew1^T as A, q==0 lanes)
//   acc := node_pre[src] (identity-A injection MFMA, b128 gathers)
//   acc += Wc^T · h1^T ; h2 = silu(acc + bc)
//   segmented reduction over sorted tgt runs -> atomicAdd sums (h2-space;
//   mw2 applied in grid_kernel by linearity of mean).
// LDS ~37 KB, weights in registers.
// ---------------------------------------------------------------------------
__global__ __launch_bounds__(256, 3) void edge_kernel(
    const int2* __restrict__ st_sorted, const float* __restrict__ node_pos,
    const float* __restrict__ grid_pos, const float* __restrict__ ori,
    const unsigned short* __restrict__ ew1t8, const float* __restrict__ eb1,
    const unsigned short* __restrict__ wct, const float* __restrict__ bc,
    const unsigned short* __restrict__ node_pre, float* __restrict__ sums, int E) {
  __shared__ __align__(16) unsigned short s_h[128 * P];
  __shared__ int s_src[128];
  __shared__ int s_tgt[128];
  __shared__ float s_eb1[128];
  __shared__ float s_bc[128];

  int tid = threadIdx.x;
  int base = blockIdx.x * 128;

  if (tid < 128) {
    s_eb1[tid] = eb1[tid];
    s_bc[tid] = bc[tid];
    int eg = base + tid;
    int s = 0, tg = -1;
    float a0 = 0.f, a1 = 0.f, a2 = 0.f, a3 = 0.f, a4 = 0.f, a5 = 0.f;
    if (eg < E) {
      int2 st = st_sorted[eg];
      s = st.x; tg = st.y;
      float px = node_pos[s * 3 + 0], py = node_pos[s * 3 + 1], pz = node_pos[s * 3 + 2];
      float rx = grid_pos[tg * 3 + 0] - px;
      float ry = grid_pos[tg * 3 + 1] - py;
      float rz = grid_pos[tg * 3 + 2] - pz;
      const float* o = &ori[(long)s * 9];
      a0 = px; a1 = py; a2 = pz;
      a3 = rx * o[0] + ry * o[3] + rz * o[6];
      a4 = rx * o[1] + ry * o[4] + rz * o[7];
      a5 = rx * o[2] + ry * o[5] + rz * o[8];
    }
    s_src[tid] = s;
    s_tgt[tid] = tg;
    uint4 w0;
    w0.x = pack2bf(a0, a1); w0.y = pack2bf(a2, a3); w0.z = pack2bf(a4, a5); w0.w = 0u;
    *(uint4*)&s_h[tid * P] = w0;   // attr row [edge][k0..7]
  }
  __syncthreads();

  int wave = tid >> 6, lane = tid & 63;
  int q = lane >> 4, l16 = lane & 15;
  int m0w = wave * 32;
  short8 z8 = (short8){0, 0, 0, 0, 0, 0, 0, 0};

  // Wc^T rows for this wave -> registers (L2-resident)
  short8 awc[2][4];
  load_A128(wct, m0w, l16, q, awc);

  // ew1^T rows (K=8) -> registers, q==0 lanes only
  short8 ae0 = z8, ae1 = z8;
  if (q == 0) {
    ae0 = *(const short8*)&ew1t8[(m0w + l16) * 8];
    ae1 = *(const short8*)&ew1t8[(m0w + 16 + l16) * 8];
  }

  // GEMM0: D[h][edge] = ew1^T · attr^T  (single K-tile)
  f32x4 acc0[2][8];
#pragma unroll
  for (int rt = 0; rt < 2; ++rt)
#pragma unroll
    for (int ct = 0; ct < 8; ++ct) acc0[rt][ct] = (f32x4){0.f, 0.f, 0.f, 0.f};
#pragma unroll
  for (int ct = 0; ct < 8; ++ct) {
    short8 b = z8;
    if (q == 0) b = *(const short8*)&s_h[(ct * 16 + l16) * P];
    acc0[0][ct] = __builtin_amdgcn_mfma_f32_16x16x32_bf16(ae0, b, acc0[0][ct], 0, 0, 0);
    acc0[1][ct] = __builtin_amdgcn_mfma_f32_16x16x32_bf16(ae1, b, acc0[1][ct], 0, 0, 0);
  }
  __syncthreads();  // attr reads done before overwrite

  epilogue_T<true>(acc0, s_eb1, s_h, m0w, l16, q);   // h1 -> s_h[edge][feat]
  __syncthreads();

  // acc := node_pre[src[edge]][feat]  via identity-A MFMA (b128 gathers)
  short8 aI;
#pragma unroll
  for (int j = 0; j < 8; ++j)
    aI[j] = ((q * 8 + j) == l16) ? (short)0x3F80 : (short)0;
  f32x4 acc[2][8];
#pragma unroll
  for (int ct = 0; ct < 8; ++ct) {
    long srow = (long)s_src[ct * 16 + l16] * 128;
#pragma unroll
    for (int rt = 0; rt < 2; ++rt) {
      short8 bnp = z8;
      if (q < 2) bnp = *(const short8*)&node_pre[srow + m0w + rt * 16 + q * 8];
      acc[rt][ct] = __builtin_amdgcn_mfma_f32_16x16x32_bf16(
          aI, bnp, (f32x4){0.f, 0.f, 0.f, 0.f}, 0, 0, 0);
    }
  }

  // GEMM1: acc += Wc^T · h1^T
  gemm_T(awc, s_h, l16, q, acc);
  __syncthreads();  // h1 reads done

  epilogue_T<true>(acc, s_bc, s_h, m0w, l16, q);     // h2 -> s_h[edge][feat]
  __syncthreads();

  // segmented reduction: thread = (colpair, 32-row chunk); flush per run.
  {
    int cp = tid & 63;
    int chunk = tid >> 6;       // 4 chunks x 32 rows
    int c0 = cp * 2;
    int row0 = chunk * 32;
    float v0 = 0.f, v1 = 0.f;
    int cur = s_tgt[row0];
    for (int r = 0; r < 32; ++r) {
      int row = row0 + r;
      int tg = s_tgt[row];
      if (tg != cur) {
        if (cur >= 0) {
          atomicAdd(&sums[(long)cur * 128 + c0], v0);
          atomicAdd(&sums[(long)cur * 128 + c0 + 1], v1);
        }
        v0 = 0.f; v1 = 0.f; cur = tg;
      }
      unsigned w = *(const unsigned*)&s_h[row * P + c0];
      v0 += bf2f((unsigned short)w);
      v1 += bf2f((unsigned short)(w >> 16));
    }
    if (cur >= 0) {
      atomicAdd(&sums[(long)cur * 128 + c0], v0);
      atomicAdd(&sums[(long)cur * 128 + c0 + 1], v1);
    }
  }
}

// ---------------------------------------------------------------------------
// Grid kernel (transposed): x = sums/clip(hist,1); y = x@mw2+mb2;
// out = silu(y@uw1+ub1)@uw2 + ub2.  Final store: packed float4.
// ---------------------------------------------------------------------------
__global__ __launch_bounds__(256, 3) void grid_kernel(
    const float* __restrict__ sums, const int* __restrict__ hist,
    const float* __restrict__ mb2, const float* __restrict__ ub1,
    const float* __restrict__ ub2, const unsigned short* __restrict__ mw2t,
    const unsigned short* __restrict__ uw1t, const unsigned short* __restrict__ uw2t,
    float* __restrict__ out, int G) {
  __shared__ __align__(16) unsigned short s_x[128 * P];
  __shared__ float s_bm[128];
  __shared__ float s_b1[128];
  __shared__ float s_b2[128];
  int tid = threadIdx.x;
  long base = (long)blockIdx.x * 128;

#pragma unroll
  for (int i = 0; i < 16; ++i) {
    int flat = tid + i * 256;       // 4096 float4 = 128 rows x 32
    int row = flat >> 5;
    int c4 = (flat & 31) << 2;
    float4 v = make_float4(0.f, 0.f, 0.f, 0.f);
    float inv = 1.f;
    if (base + row < G) {
      v = *(const float4*)&sums[(base + row) * 128 + c4];
      int c = hist[base + row];
      inv = 1.f / (float)(c < 1 ? 1 : c);
    }
    uint2 w; w.x = pack2bf(v.x * inv, v.y * inv); w.y = pack2bf(v.z * inv, v.w * inv);
    *(uint2*)&s_x[row * P + c4] = w;
  }
  if (tid < 128) { s_bm[tid] = mb2[tid]; s_b1[tid] = ub1[tid]; s_b2[tid] = ub2[tid]; }
  __syncthreads();

  int wave = tid >> 6, lane = tid & 63;
  int q = lane >> 4, l16 = lane & 15;
  int m0w = wave * 32;

  f32x4 acc[2][8];
  short8 aw[2][4];

  // GEMM A: grid_feat = x@mw2 + mb2 (no activation)
  load_A128(mw2t, m0w, l16, q, aw);
#pragma unroll
  for (int rt = 0; rt < 2; ++rt)
#pragma unroll
    for (int ct = 0; ct < 8; ++ct) acc[rt][ct] = (f32x4){0.f, 0.f, 0.f, 0.f};
  gemm_T(aw, s_x, l16, q, acc);
  __syncthreads();
  epilogue_T<false>(acc, s_bm, s_x, m0w, l16, q);
  __syncthreads();

  // GEMM B: silu(y@uw1 + ub1)
  load_A128(uw1t, m0w, l16, q, aw);
#pragma unroll
  for (int rt = 0; rt < 2; ++rt)
#pragma unroll
    for (int ct = 0; ct < 8; ++ct) acc[rt][ct] = (f32x4){0.f, 0.f, 0.f, 0.f};
  gemm_T(aw, s_x, l16, q, acc);
  __syncthreads();
  epilogue_T<true>(acc, s_b1, s_x, m0w, l16, q);
  __syncthreads();

  // GEMM C: out = h@uw2 + ub2  (fp32 float4 stores)
  load_A128(uw2t, m0w, l16, q, aw);
#pragma unroll
  for (int rt = 0; rt < 2; ++rt)
#pragma unroll
    for (int ct = 0; ct < 8; ++ct) acc[rt][ct] = (f32x4){0.f, 0.f, 0.f, 0.f};
  gemm_T(aw, s_x, l16, q, acc);

#pragma unroll
  for (int rt = 0; rt < 2; ++rt) {
    int f0 = m0w + rt * 16 + q * 4;
    float b0 = s_b2[f0], b1 = s_b2[f0 + 1], b2 = s_b2[f0 + 2], b3 = s_b2[f0 + 3];
#pragma unroll
    for (int ct = 0; ct < 8; ++ct) {
      long g = base + ct * 16 + l16;
      if (g < G) {
        float4 o = make_float4(acc[rt][ct][0] + b0, acc[rt][ct][1] + b1,
                               acc[rt][ct][2] + b2, acc[rt][ct][3] + b3);
        *(float4*)&out[g * 128 + f0] = o;
      }
    }
  }
}

extern "C" void kernel_launch(void* const* d_in, const int* in_sizes, int n_in,
                              void* d_out, int out_size, void* d_ws, size_t ws_size,
                              hipStream_t stream) {
  const float* x    = (const float*)d_in[0];
  const float* npos = (const float*)d_in[1];
  const float* gpos = (const float*)d_in[2];
  const int*   eidx = (const int*)d_in[3];
  const float* ori  = (const float*)d_in[4];
  const float* nw1 = (const float*)d_in[5];
  const float* nb1 = (const float*)d_in[6];
  const float* nw2 = (const float*)d_in[7];
  const float* nb2 = (const float*)d_in[8];
  const float* ew1 = (const float*)d_in[9];
  const float* eb1 = (const float*)d_in[10];
  const float* ew2 = (const float*)d_in[11];
  const float* eb2 = (const float*)d_in[12];
  const float* mw1 = (const float*)d_in[13];
  const float* mb1 = (const float*)d_in[14];
  const float* mw2 = (const float*)d_in[15];
  const float* mb2 = (const float*)d_in[16];
  const float* uw1 = (const float*)d_in[17];
  const float* ub1 = (const float*)d_in[18];
  const float* uw2 = (const float*)d_in[19];
  const float* ub2 = (const float*)d_in[20];

  int N = in_sizes[0] / 128;
  int G = in_sizes[2] / 3;
  int E = in_sizes[3] / 2;

  // ws layout within R1's proven footprint (~43 MB). Sorted-edge buffer
  // (E*8 = 8 MB) lives in d_out (16.8 MB) — dead until grid_kernel (last
  // launch); stream order makes the reuse safe.
  char* ws = (char*)d_ws;
  size_t off = 0;
  float* sums = (float*)(ws + off);            off += (size_t)G * 128 * 4;
  int* hist = (int*)(ws + off);                off += (size_t)G * 4;
  int* cursor = (int*)(ws + off);              off += (size_t)G * 4;
  unsigned short* node_pre = (unsigned short*)(ws + off); off += (size_t)N * 128 * 2;
  off = (off + 255) & ~(size_t)255;
  unsigned short* w_nw1t = (unsigned short*)(ws + off); off += 128 * 128 * 2;
  unsigned short* w_wnt  = (unsigned short*)(ws + off); off += 128 * 128 * 2;
  unsigned short* w_wct  = (unsigned short*)(ws + off); off += 128 * 128 * 2;
  unsigned short* w_mw2t = (unsigned short*)(ws + off); off += 128 * 128 * 2;
  unsigned short* w_uw1t = (unsigned short*)(ws + off); off += 128 * 128 * 2;
  unsigned short* w_uw2t = (unsigned short*)(ws + off); off += 128 * 128 * 2;
  unsigned short* w_ew1t8 = (unsigned short*)(ws + off); off += 128 * 8 * 2;
  float* bn = (float*)(ws + off); off += 128 * 4;
  float* bc = (float*)(ws + off); off += 128 * 4;

  int2* st_sorted = (int2*)d_out;   // scratch until grid_kernel overwrites it

  // zero sums + hist (contiguous)
  hipMemsetAsync(sums, 0, ((size_t)G * 128 + G) * 4, stream);

  fold_weights_kernel<<<128, 128, 0, stream>>>(nw1, nw2, nb2, ew2, eb2, mw1, mb1,
                                               mw2, uw1, uw2, ew1, w_nw1t, w_wnt,
                                               w_wct, w_mw2t, w_uw1t, w_uw2t,
                                               w_ew1t8, bn, bc);
  hist_kernel<<<(E + 511) / 512, 512, 0, stream>>>(eidx, hist, E);
  scan_kernel<<<1, 1024, 0, stream>>>(hist, cursor, G);
  scatter_kernel<<<(E + 511) / 512, 512, 0, stream>>>(eidx, cursor, st_sorted, E);
  node_kernel<<<(N + 127) / 128, 256, 0, stream>>>(x, nb1, w_nw1t, w_wnt, bn,
                                                   node_pre, N);
  edge_kernel<<<(E + 127) / 128, 256, 0, stream>>>(st_sorted, npos, gpos, ori,
                                                   w_ew1t8, eb1, w_wct, bc,
                                                   node_pre, sums, E);
  grid_kernel<<<(G + 127) / 128, 256, 0, stream>>>(sums, hist, mb2, ub1, ub2,
                                                   w_mw2t, w_uw1t, w_uw2t,
                                                   (float*)d_out, G);
}

// Round 8
// 508.684 us; speedup vs baseline: 1.4306x; 1.0845x over previous
//
#include <hip/hip_runtime.h>

// LDS row pitch in ushorts: 136*2=272B -> dword stride 68 -> bank step 4 ->
// only 2-way aliasing (free). 272 is a multiple of 16 -> rows stay 16B-aligned.
#define P 136

typedef __attribute__((ext_vector_type(8))) short short8;
typedef __attribute__((ext_vector_type(4))) float f32x4;

__device__ __forceinline__ unsigned short f2bf(float f) {
  union { float f; unsigned u; } v; v.f = f;
  unsigned u = v.u + 0x7fffu + ((v.u >> 16) & 1u);   // RNE
  return (unsigned short)(u >> 16);
}
__device__ __forceinline__ float bf2f(unsigned short h) {
  union { unsigned u; float f; } v; v.u = ((unsigned)h) << 16;
  return v.f;
}
// pack two floats -> bf16x2 dword (RNE both)
__device__ __forceinline__ unsigned pack2bf(float x, float y) {
  union { float f; unsigned u; } a, b; a.f = x; b.f = y;
  unsigned lo = (a.u + 0x7fffu + ((a.u >> 16) & 1u)) >> 16;
  unsigned hi = (b.u + 0x7fffu + ((b.u >> 16) & 1u)) & 0xffff0000u;
  return lo | hi;
}
// silu via hw approx rcp: exact-div sequence (~10 instrs) -> 5 instrs.
// rcp rel err ~1e-7 << bf16 rounding (4e-3) -> numerically invisible.
__device__ __forceinline__ float silu_f(float x) {
  float e = __expf(-x);
  return x * __builtin_amdgcn_rcpf(1.0f + e);
}

// Transposed-GEMM building blocks. D[m=feat][n=row]:
//   A = W^T [feat][k] in REGISTERS (8 x short8 per wave, rows m0w..m0w+31)
//   B = X   [row][k]  in LDS, pitch P (contiguous b128 reads)
// C/D: lane holds n(row)=l16 (per ct tile), m(feat)=m0w+rt*16+q*4+r -> 4
// consecutive feature cols per lane => packed 8B epilogue stores.
__device__ __forceinline__ void load_A128(const unsigned short* __restrict__ W,
                                          int m0w, int l16, int q, short8 a[2][4]) {
#pragma unroll
  for (int rt = 0; rt < 2; ++rt)
#pragma unroll
    for (int kt = 0; kt < 4; ++kt)
      a[rt][kt] = *(const short8*)&W[(m0w + rt * 16 + l16) * 128 + kt * 32 + q * 8];
}

__device__ __forceinline__ void gemm_T(const short8 a[2][4],
                                       const unsigned short* sB,
                                       int l16, int q, f32x4 acc[2][8]) {
#pragma unroll
  for (int kt = 0; kt < 4; ++kt)
#pragma unroll
    for (int ct = 0; ct < 8; ++ct) {
      short8 b = *(const short8*)&sB[(ct * 16 + l16) * P + kt * 32 + q * 8];
      acc[0][ct] = __builtin_amdgcn_mfma_f32_16x16x32_bf16(a[0][kt], b, acc[0][ct], 0, 0, 0);
      acc[1][ct] = __builtin_amdgcn_mfma_f32_16x16x32_bf16(a[1][kt], b, acc[1][ct], 0, 0, 0);
    }
}

template <bool SILU>
__device__ __forceinline__ void epilogue_T(const f32x4 acc[2][8], const float* bias,
                                           unsigned short* sOut, int m0w, int l16,
                                           int q) {
#pragma unroll
  for (int rt = 0; rt < 2; ++rt) {
    int f0 = m0w + rt * 16 + q * 4;
    float4 bv = *(const float4*)&bias[f0];   // bias arrays are __align__(16)
#pragma unroll
    for (int ct = 0; ct < 8; ++ct) {
      float v0 = acc[rt][ct][0] + bv.x, v1 = acc[rt][ct][1] + bv.y;
      float v2 = acc[rt][ct][2] + bv.z, v3 = acc[rt][ct][3] + bv.w;
      if (SILU) { v0 = silu_f(v0); v1 = silu_f(v1); v2 = silu_f(v2); v3 = silu_f(v3); }
      uint2 w; w.x = pack2bf(v0, v1); w.y = pack2bf(v2, v3);
      *(uint2*)&sOut[(ct * 16 + l16) * P + f0] = w;
    }
  }
}

// ---------------------------------------------------------------------------
// Merged fold + hist kernel (256 threads):
//   blocks [0,64):  weight folding, b = blk*2 + (tid>>7), t = tid&127
//   blocks [64,..): histogram of tgt
// ---------------------------------------------------------------------------
__global__ __launch_bounds__(256) void fold_hist_kernel(
    const float* __restrict__ nw1, const float* __restrict__ nw2,
    const float* __restrict__ nb2, const float* __restrict__ ew2,
    const float* __restrict__ eb2, const float* __restrict__ mw1,
    const float* __restrict__ mb1, const float* __restrict__ mw2,
    const float* __restrict__ uw1, const float* __restrict__ uw2,
    const float* __restrict__ ew1,
    unsigned short* __restrict__ nw1t, unsigned short* __restrict__ wnt,
    unsigned short* __restrict__ wct, unsigned short* __restrict__ mw2t,
    unsigned short* __restrict__ uw1t, unsigned short* __restrict__ uw2t,
    unsigned short* __restrict__ ew1t8,
    float* __restrict__ bn, float* __restrict__ bc,
    const int* __restrict__ eidx, int* __restrict__ hist, int E) {
  if (blockIdx.x >= 64) {
    int e = (blockIdx.x - 64) * 256 + threadIdx.x;
    if (e < E) atomicAdd(&hist[eidx[E + e]], 1);
    return;
  }
  int b = blockIdx.x * 2 + (threadIdx.x >> 7);  // output col
  int t = threadIdx.x & 127;                    // input row
  float accn = 0.f, accc = 0.f;
  for (int j = 0; j < 128; ++j) {
    accn += nw2[t * 128 + j] * mw1[j * 128 + b];
    accc += ew2[t * 128 + j] * mw1[(128 + j) * 128 + b];
  }
  wnt[b * 128 + t] = f2bf(accn);
  wct[b * 128 + t] = f2bf(accc);
  nw1t[b * 128 + t] = f2bf(nw1[t * 128 + b]);
  mw2t[b * 128 + t] = f2bf(mw2[t * 128 + b]);
  uw1t[b * 128 + t] = f2bf(uw1[t * 128 + b]);
  uw2t[b * 128 + t] = f2bf(uw2[t * 128 + b]);
  if (t < 8) ew1t8[b * 8 + t] = (t < 6) ? f2bf(ew1[t * 128 + b]) : (unsigned short)0;
  if (b == 0) {
    float sn = 0.f, sc = 0.f;
    for (int j = 0; j < 128; ++j) {
      sn += nb2[j] * mw1[j * 128 + t];
      sc += eb2[j] * mw1[(128 + j) * 128 + t];
    }
    bn[t] = sn;
    bc[t] = mb1[t] + sc;
  }
}

__global__ __launch_bounds__(1024) void scan_kernel(const int* __restrict__ hist,
                                                    int* __restrict__ cursor, int G) {
  __shared__ int s[1024];
  int tid = threadIdx.x;
  int per = (G + 1023) >> 10;
  int b0 = tid * per;
  int sum = 0;
  for (int i = 0; i < per; ++i)
    if (b0 + i < G) sum += hist[b0 + i];
  s[tid] = sum;
  __syncthreads();
  for (int off = 1; off < 1024; off <<= 1) {
    int v = (tid >= off) ? s[tid - off] : 0;
    __syncthreads();
    s[tid] += v;
    __syncthreads();
  }
  int run = s[tid] - sum;  // exclusive prefix
  for (int i = 0; i < per; ++i)
    if (b0 + i < G) {
      cursor[b0 + i] = run;
      run += hist[b0 + i];
    }
}

// ---------------------------------------------------------------------------
// Merged scatter + node kernel (256 threads):
//   blocks [0,nScat):   scatter (src,tgt) into sorted position (atomic cursor)
//   blocks [nScat,..):  node MLP: node_pre = silu(x@nw1+nb1) @ Wn + bn
// Independent work — scatter's contended atomics overlap node's MFMA compute.
// ---------------------------------------------------------------------------
__global__ __launch_bounds__(256, 3) void scatter_node_kernel(
    const int* __restrict__ eidx, int* __restrict__ cursor,
    int2* __restrict__ st, int E, int nScat,
    const float* __restrict__ x, const float* __restrict__ nb1,
    const unsigned short* __restrict__ nw1t, const unsigned short* __restrict__ wnt,
    const float* __restrict__ bn, unsigned short* __restrict__ node_pre, int N) {
  __shared__ __align__(16) unsigned short s_x[128 * P];
  __shared__ __align__(16) float s_b1[128];
  __shared__ __align__(16) float s_bn[128];

  if (blockIdx.x < (unsigned)nScat) {
    int e = blockIdx.x * 256 + threadIdx.x;
    if (e < E) {
      int tg = eidx[E + e];
      int pos = atomicAdd(&cursor[tg], 1);
      st[pos] = make_int2(eidx[e], tg);
    }
    return;
  }

  int tid = threadIdx.x;
  long base = (long)(blockIdx.x - nScat) * 128;

#pragma unroll
  for (int i = 0; i < 16; ++i) {
    int flat = tid + i * 256;      // 4096 float4 = 128 rows x 32
    int row = flat >> 5;
    int c4 = (flat & 31) << 2;
    float4 v = make_float4(0.f, 0.f, 0.f, 0.f);
    if (base + row < N) v = *(const float4*)&x[(base + row) * 128 + c4];
    uint2 w; w.x = pack2bf(v.x, v.y); w.y = pack2bf(v.z, v.w);
    *(uint2*)&s_x[row * P + c4] = w;
  }
  if (tid < 128) { s_b1[tid] = nb1[tid]; s_bn[tid] = bn[tid]; }
  __syncthreads();

  int wave = tid >> 6, lane = tid & 63;
  int q = lane >> 4, l16 = lane & 15;
  int m0w = wave * 32;

  short8 a1[2][4];
  load_A128(nw1t, m0w, l16, q, a1);
  f32x4 acc[2][8];
#pragma unroll
  for (int rt = 0; rt < 2; ++rt)
#pragma unroll
    for (int ct = 0; ct < 8; ++ct) acc[rt][ct] = (f32x4){0.f, 0.f, 0.f, 0.f};
  gemm_T(a1, s_x, l16, q, acc);
  __syncthreads();
  epilogue_T<true>(acc, s_b1, s_x, m0w, l16, q);
  __syncthreads();

  short8 a2[2][4];
  load_A128(wnt, m0w, l16, q, a2);
#pragma unroll
  for (int rt = 0; rt < 2; ++rt)
#pragma unroll
    for (int ct = 0; ct < 8; ++ct) acc[rt][ct] = (f32x4){0.f, 0.f, 0.f, 0.f};
  gemm_T(a2, s_x, l16, q, acc);

  // store node_pre[node][feat] packed 8B
#pragma unroll
  for (int rt = 0; rt < 2; ++rt) {
    int f0 = m0w + rt * 16 + q * 4;
    float4 bv = *(const float4*)&s_bn[f0];
#pragma unroll
    for (int ct = 0; ct < 8; ++ct) {
      long n = base + ct * 16 + l16;
      if (n < N) {
        uint2 w;
        w.x = pack2bf(acc[rt][ct][0] + bv.x, acc[rt][ct][1] + bv.y);
        w.y = pack2bf(acc[rt][ct][2] + bv.z, acc[rt][ct][3] + bv.w);
        *(uint2*)&node_pre[n * 128 + f0] = w;
      }
    }
  }
}

// ---------------------------------------------------------------------------
// Edge kernel (sorted edges, transposed GEMMs), 128 edges / 256 threads.
//   attr(K=8) --MFMA--> h1 = silu(.+eb1)        (ew1^T as A, q==0 lanes)
//   acc := node_pre[src] (identity-A injection MFMA, b128 gathers)
//   acc += Wc^T · h1^T ; h2 = silu(acc + bc)
//   segmented reduction over sorted tgt runs -> atomicAdd sums (h2-space;
//   mw2 applied in grid_kernel by linearity of mean).
// LDS 36.9 KB -> 4 blocks/CU (LDS-capped), weights in registers.
// ---------------------------------------------------------------------------
__global__ __launch_bounds__(256, 3) void edge_kernel(
    const int2* __restrict__ st_sorted, const float* __restrict__ node_pos,
    const float* __restrict__ grid_pos, const float* __restrict__ ori,
    const unsigned short* __restrict__ ew1t8, const float* __restrict__ eb1,
    const unsigned short* __restrict__ wct, const float* __restrict__ bc,
    const unsigned short* __restrict__ node_pre, float* __restrict__ sums, int E) {
  __shared__ __align__(16) unsigned short s_h[128 * P];
  __shared__ int s_src[128];
  __shared__ int s_tgt[128];
  __shared__ __align__(16) float s_eb1[128];
  __shared__ __align__(16) float s_bc[128];

  int tid = threadIdx.x;
  int base = blockIdx.x * 128;

  if (tid < 128) {
    s_eb1[tid] = eb1[tid];
    s_bc[tid] = bc[tid];
    int eg = base + tid;
    int s = 0, tg = -1;
    float a0 = 0.f, a1 = 0.f, a2 = 0.f, a3 = 0.f, a4 = 0.f, a5 = 0.f;
    if (eg < E) {
      int2 st = st_sorted[eg];
      s = st.x; tg = st.y;
      float px = node_pos[s * 3 + 0], py = node_pos[s * 3 + 1], pz = node_pos[s * 3 + 2];
      float rx = grid_pos[tg * 3 + 0] - px;
      float ry = grid_pos[tg * 3 + 1] - py;
      float rz = grid_pos[tg * 3 + 2] - pz;
      const float* o = &ori[(long)s * 9];
      a0 = px; a1 = py; a2 = pz;
      a3 = rx * o[0] + ry * o[3] + rz * o[6];
      a4 = rx * o[1] + ry * o[4] + rz * o[7];
      a5 = rx * o[2] + ry * o[5] + rz * o[8];
    }
    s_src[tid] = s;
    s_tgt[tid] = tg;
    uint4 w0;
    w0.x = pack2bf(a0, a1); w0.y = pack2bf(a2, a3); w0.z = pack2bf(a4, a5); w0.w = 0u;
    *(uint4*)&s_h[tid * P] = w0;   // attr row [edge][k0..7]
  }
  __syncthreads();

  int wave = tid >> 6, lane = tid & 63;
  int q = lane >> 4, l16 = lane & 15;
  int m0w = wave * 32;
  short8 z8 = (short8){0, 0, 0, 0, 0, 0, 0, 0};

  // Wc^T rows for this wave -> registers (L2-resident)
  short8 awc[2][4];
  load_A128(wct, m0w, l16, q, awc);

  // ew1^T rows (K=8) -> registers, q==0 lanes only
  short8 ae0 = z8, ae1 = z8;
  if (q == 0) {
    ae0 = *(const short8*)&ew1t8[(m0w + l16) * 8];
    ae1 = *(const short8*)&ew1t8[(m0w + 16 + l16) * 8];
  }

  // GEMM0: D[h][edge] = ew1^T · attr^T  (single K-tile)
  f32x4 acc0[2][8];
#pragma unroll
  for (int rt = 0; rt < 2; ++rt)
#pragma unroll
    for (int ct = 0; ct < 8; ++ct) acc0[rt][ct] = (f32x4){0.f, 0.f, 0.f, 0.f};
#pragma unroll
  for (int ct = 0; ct < 8; ++ct) {
    short8 b = z8;
    if (q == 0) b = *(const short8*)&s_h[(ct * 16 + l16) * P];
    acc0[0][ct] = __builtin_amdgcn_mfma_f32_16x16x32_bf16(ae0, b, acc0[0][ct], 0, 0, 0);
    acc0[1][ct] = __builtin_amdgcn_mfma_f32_16x16x32_bf16(ae1, b, acc0[1][ct], 0, 0, 0);
  }
  __syncthreads();  // attr reads done before overwrite

  epilogue_T<true>(acc0, s_eb1, s_h, m0w, l16, q);   // h1 -> s_h[edge][feat]
  __syncthreads();

  // acc := node_pre[src[edge]][feat]  via identity-A MFMA (b128 gathers)
  short8 aI;
#pragma unroll
  for (int j = 0; j < 8; ++j)
    aI[j] = ((q * 8 + j) == l16) ? (short)0x3F80 : (short)0;
  f32x4 acc[2][8];
#pragma unroll
  for (int ct = 0; ct < 8; ++ct) {
    long srow = (long)s_src[ct * 16 + l16] * 128;
#pragma unroll
    for (int rt = 0; rt < 2; ++rt) {
      short8 bnp = z8;
      if (q < 2) bnp = *(const short8*)&node_pre[srow + m0w + rt * 16 + q * 8];
      acc[rt][ct] = __builtin_amdgcn_mfma_f32_16x16x32_bf16(
          aI, bnp, (f32x4){0.f, 0.f, 0.f, 0.f}, 0, 0, 0);
    }
  }

  // GEMM1: acc += Wc^T · h1^T
  gemm_T(awc, s_h, l16, q, acc);
  __syncthreads();  // h1 reads done

  epilogue_T<true>(acc, s_bc, s_h, m0w, l16, q);     // h2 -> s_h[edge][feat]
  __syncthreads();

  // segmented reduction: thread = (colpair, 32-row chunk); flush per run.
  {
    int cp = tid & 63;
    int chunk = tid >> 6;       // 4 chunks x 32 rows
    int c0 = cp * 2;
    int row0 = chunk * 32;
    float v0 = 0.f, v1 = 0.f;
    int cur = s_tgt[row0];
    for (int r = 0; r < 32; ++r) {
      int row = row0 + r;
      int tg = s_tgt[row];
      if (tg != cur) {
        if (cur >= 0) {
          atomicAdd(&sums[(long)cur * 128 + c0], v0);
          atomicAdd(&sums[(long)cur * 128 + c0 + 1], v1);
        }
        v0 = 0.f; v1 = 0.f; cur = tg;
      }
      unsigned w = *(const unsigned*)&s_h[row * P + c0];
      v0 += bf2f((unsigned short)w);
      v1 += bf2f((unsigned short)(w >> 16));
    }
    if (cur >= 0) {
      atomicAdd(&sums[(long)cur * 128 + c0], v0);
      atomicAdd(&sums[(long)cur * 128 + c0 + 1], v1);
    }
  }
}

// ---------------------------------------------------------------------------
// Grid kernel (transposed): x = sums/clip(hist,1); y = x@mw2+mb2;
// out = silu(y@uw1+ub1)@uw2 + ub2.  Final store: packed float4.
// ---------------------------------------------------------------------------
__global__ __launch_bounds__(256, 3) void grid_kernel(
    const float* __restrict__ sums, const int* __restrict__ hist,
    const float* __restrict__ mb2, const float* __restrict__ ub1,
    const float* __restrict__ ub2, const unsigned short* __restrict__ mw2t,
    const unsigned short* __restrict__ uw1t, const unsigned short* __restrict__ uw2t,
    float* __restrict__ out, int G) {
  __shared__ __align__(16) unsigned short s_x[128 * P];
  __shared__ __align__(16) float s_bm[128];
  __shared__ __align__(16) float s_b1[128];
  __shared__ __align__(16) float s_b2[128];
  int tid = threadIdx.x;
  long base = (long)blockIdx.x * 128;

#pragma unroll
  for (int i = 0; i < 16; ++i) {
    int flat = tid + i * 256;       // 4096 float4 = 128 rows x 32
    int row = flat >> 5;
    int c4 = (flat & 31) << 2;
    float4 v = make_float4(0.f, 0.f, 0.f, 0.f);
    float inv = 1.f;
    if (base + row < G) {
      v = *(const float4*)&sums[(base + row) * 128 + c4];
      int c = hist[base + row];
      inv = __builtin_amdgcn_rcpf((float)(c < 1 ? 1 : c));
    }
    uint2 w; w.x = pack2bf(v.x * inv, v.y * inv); w.y = pack2bf(v.z * inv, v.w * inv);
    *(uint2*)&s_x[row * P + c4] = w;
  }
  if (tid < 128) { s_bm[tid] = mb2[tid]; s_b1[tid] = ub1[tid]; s_b2[tid] = ub2[tid]; }
  __syncthreads();

  int wave = tid >> 6, lane = tid & 63;
  int q = lane >> 4, l16 = lane & 15;
  int m0w = wave * 32;

  f32x4 acc[2][8];
  short8 aw[2][4];

  // GEMM A: grid_feat = x@mw2 + mb2 (no activation)
  load_A128(mw2t, m0w, l16, q, aw);
#pragma unroll
  for (int rt = 0; rt < 2; ++rt)
#pragma unroll
    for (int ct = 0; ct < 8; ++ct) acc[rt][ct] = (f32x4){0.f, 0.f, 0.f, 0.f};
  gemm_T(aw, s_x, l16, q, acc);
  __syncthreads();
  epilogue_T<false>(acc, s_bm, s_x, m0w, l16, q);
  __syncthreads();

  // GEMM B: silu(y@uw1 + ub1)
  load_A128(uw1t, m0w, l16, q, aw);
#pragma unroll
  for (int rt = 0; rt < 2; ++rt)
#pragma unroll
    for (int ct = 0; ct < 8; ++ct) acc[rt][ct] = (f32x4){0.f, 0.f, 0.f, 0.f};
  gemm_T(aw, s_x, l16, q, acc);
  __syncthreads();
  epilogue_T<true>(acc, s_b1, s_x, m0w, l16, q);
  __syncthreads();

  // GEMM C: out = h@uw2 + ub2  (fp32 float4 stores)
  load_A128(uw2t, m0w, l16, q, aw);
#pragma unroll
  for (int rt = 0; rt < 2; ++rt)
#pragma unroll
    for (int ct = 0; ct < 8; ++ct) acc[rt][ct] = (f32x4){0.f, 0.f, 0.f, 0.f};
  gemm_T(aw, s_x, l16, q, acc);

#pragma unroll
  for (int rt = 0; rt < 2; ++rt) {
    int f0 = m0w + rt * 16 + q * 4;
    float4 bv = *(const float4*)&s_b2[f0];
#pragma unroll
    for (int ct = 0; ct < 8; ++ct) {
      long g = base + ct * 16 + l16;
      if (g < G) {
        float4 o = make_float4(acc[rt][ct][0] + bv.x, acc[rt][ct][1] + bv.y,
                               acc[rt][ct][2] + bv.z, acc[rt][ct][3] + bv.w);
        *(float4*)&out[g * 128 + f0] = o;
      }
    }
  }
}

extern "C" void kernel_launch(void* const* d_in, const int* in_sizes, int n_in,
                              void* d_out, int out_size, void* d_ws, size_t ws_size,
                              hipStream_t stream) {
  const float* x    = (const float*)d_in[0];
  const float* npos = (const float*)d_in[1];
  const float* gpos = (const float*)d_in[2];
  const int*   eidx = (const int*)d_in[3];
  const float* ori  = (const float*)d_in[4];
  const float* nw1 = (const float*)d_in[5];
  const float* nb1 = (const float*)d_in[6];
  const float* nw2 = (const float*)d_in[7];
  const float* nb2 = (const float*)d_in[8];
  const float* ew1 = (const float*)d_in[9];
  const float* eb1 = (const float*)d_in[10];
  const float* ew2 = (const float*)d_in[11];
  const float* eb2 = (const float*)d_in[12];
  const float* mw1 = (const float*)d_in[13];
  const float* mb1 = (const float*)d_in[14];
  const float* mw2 = (const float*)d_in[15];
  const float* mb2 = (const float*)d_in[16];
  const float* uw1 = (const float*)d_in[17];
  const float* ub1 = (const float*)d_in[18];
  const float* uw2 = (const float*)d_in[19];
  const float* ub2 = (const float*)d_in[20];

  int N = in_sizes[0] / 128;
  int G = in_sizes[2] / 3;
  int E = in_sizes[3] / 2;

  // ws layout within R1's proven footprint (~43 MB). Sorted-edge buffer
  // (E*8 = 8 MB) lives in d_out (16.8 MB) — dead until grid_kernel (last
  // launch); stream order makes the reuse safe.
  char* ws = (char*)d_ws;
  size_t off = 0;
  float* sums = (float*)(ws + off);            off += (size_t)G * 128 * 4;
  int* hist = (int*)(ws + off);                off += (size_t)G * 4;
  int* cursor = (int*)(ws + off);              off += (size_t)G * 4;
  unsigned short* node_pre = (unsigned short*)(ws + off); off += (size_t)N * 128 * 2;
  off = (off + 255) & ~(size_t)255;
  unsigned short* w_nw1t = (unsigned short*)(ws + off); off += 128 * 128 * 2;
  unsigned short* w_wnt  = (unsigned short*)(ws + off); off += 128 * 128 * 2;
  unsigned short* w_wct  = (unsigned short*)(ws + off); off += 128 * 128 * 2;
  unsigned short* w_mw2t = (unsigned short*)(ws + off); off += 128 * 128 * 2;
  unsigned short* w_uw1t = (unsigned short*)(ws + off); off += 128 * 128 * 2;
  unsigned short* w_uw2t = (unsigned short*)(ws + off); off += 128 * 128 * 2;
  unsigned short* w_ew1t8 = (unsigned short*)(ws + off); off += 128 * 8 * 2;
  float* bn = (float*)(ws + off); off += 128 * 4;
  float* bc = (float*)(ws + off); off += 128 * 4;

  int2* st_sorted = (int2*)d_out;   // scratch until grid_kernel overwrites it

  int nScat = (E + 255) / 256;
  int nNode = (N + 127) / 128;
  int nHist = (E + 255) / 256;

  // zero sums + hist (contiguous)
  hipMemsetAsync(sums, 0, ((size_t)G * 128 + G) * 4, stream);

  fold_hist_kernel<<<64 + nHist, 256, 0, stream>>>(
      nw1, nw2, nb2, ew2, eb2, mw1, mb1, mw2, uw1, uw2, ew1,
      w_nw1t, w_wnt, w_wct, w_mw2t, w_uw1t, w_uw2t, w_ew1t8, bn, bc,
      eidx, hist, E);
  scan_kernel<<<1, 1024, 0, stream>>>(hist, cursor, G);
  scatter_node_kernel<<<nScat + nNode, 256, 0, stream>>>(
      eidx, cursor, st_sorted, E, nScat,
      x, nb1, w_nw1t, w_wnt, bn, node_pre, N);
  edge_kernel<<<(E + 127) / 128, 256, 0, stream>>>(st_sorted, npos, gpos, ori,
                                                   w_ew1t8, eb1, w_wct, bc,
                                                   node_pre, sums, E);
  grid_kernel<<<(G + 127) / 128, 256, 0, stream>>>(sums, hist, mb2, ub1, ub2,
                                                   w_mw2t, w_uw1t, w_uw2t,
                                                   (float*)d_out, G);
}

// Round 9
// 501.794 us; speedup vs baseline: 1.4502x; 1.0137x over previous
//
#include <hip/hip_runtime.h>

// LDS row pitch in ushorts: 136*2=272B -> dword stride 68 -> bank step 4 ->
// only 2-way aliasing (free). 272 is a multiple of 16 -> rows stay 16B-aligned.
#define P 136

typedef __attribute__((ext_vector_type(8))) short short8;
typedef __attribute__((ext_vector_type(4))) float f32x4;

__device__ __forceinline__ unsigned short f2bf(float f) {
  union { float f; unsigned u; } v; v.f = f;
  unsigned u = v.u + 0x7fffu + ((v.u >> 16) & 1u);   // RNE
  return (unsigned short)(u >> 16);
}
__device__ __forceinline__ float bf2f(unsigned short h) {
  union { unsigned u; float f; } v; v.u = ((unsigned)h) << 16;
  return v.f;
}
// pack two floats -> bf16x2 dword in 3 VALU ops:
// round-half-away (u+0x8000, trunc hi16) + v_perm_b32 merge.
// vs RNE: differs only at exact ties (+0.5 ulp bias there) — invisible at bf16.
__device__ __forceinline__ unsigned pack2bf(float x, float y) {
  union { float f; unsigned u; } a, b; a.f = x; b.f = y;
  return __builtin_amdgcn_perm(b.u + 0x8000u, a.u + 0x8000u, 0x07060302u);
}
// silu via hw approx rcp (rel err ~1e-7 << bf16 rounding).
__device__ __forceinline__ float silu_f(float x) {
  float e = __expf(-x);
  return x * __builtin_amdgcn_rcpf(1.0f + e);
}

// Transposed-GEMM building blocks. D[m=feat][n=row]:
//   A = W^T [feat][k] in REGISTERS (8 x short8 per wave, rows m0w..m0w+31)
//   B = X   [row][k]  in LDS, pitch P (contiguous b128 reads)
// C/D: lane holds n(row)=l16 (per ct tile), m(feat)=m0w+rt*16+q*4+r -> 4
// consecutive feature cols per lane => packed 8B epilogue stores.
__device__ __forceinline__ void load_A128(const unsigned short* __restrict__ W,
                                          int m0w, int l16, int q, short8 a[2][4]) {
#pragma unroll
  for (int rt = 0; rt < 2; ++rt)
#pragma unroll
    for (int kt = 0; kt < 4; ++kt)
      a[rt][kt] = *(const short8*)&W[(m0w + rt * 16 + l16) * 128 + kt * 32 + q * 8];
}

__device__ __forceinline__ void gemm_T(const short8 a[2][4],
                                       const unsigned short* sB,
                                       int l16, int q, f32x4 acc[2][8]) {
#pragma unroll
  for (int kt = 0; kt < 4; ++kt)
#pragma unroll
    for (int ct = 0; ct < 8; ++ct) {
      short8 b = *(const short8*)&sB[(ct * 16 + l16) * P + kt * 32 + q * 8];
      acc[0][ct] = __builtin_amdgcn_mfma_f32_16x16x32_bf16(a[0][kt], b, acc[0][ct], 0, 0, 0);
      acc[1][ct] = __builtin_amdgcn_mfma_f32_16x16x32_bf16(a[1][kt], b, acc[1][ct], 0, 0, 0);
    }
}

template <bool SILU>
__device__ __forceinline__ void epilogue_T(const f32x4 acc[2][8], const float* bias,
                                           unsigned short* sOut, int m0w, int l16,
                                           int q) {
#pragma unroll
  for (int rt = 0; rt < 2; ++rt) {
    int f0 = m0w + rt * 16 + q * 4;
    float4 bv = *(const float4*)&bias[f0];   // bias arrays are __align__(16)
#pragma unroll
    for (int ct = 0; ct < 8; ++ct) {
      float v0 = acc[rt][ct][0] + bv.x, v1 = acc[rt][ct][1] + bv.y;
      float v2 = acc[rt][ct][2] + bv.z, v3 = acc[rt][ct][3] + bv.w;
      if (SILU) { v0 = silu_f(v0); v1 = silu_f(v1); v2 = silu_f(v2); v3 = silu_f(v3); }
      uint2 w; w.x = pack2bf(v0, v1); w.y = pack2bf(v2, v3);
      *(uint2*)&sOut[(ct * 16 + l16) * P + f0] = w;
    }
  }
}

// ---------------------------------------------------------------------------
// Merged fold + hist kernel (256 threads):
//   blocks [0,64):  weight folding, b = blk*2 + (tid>>7), t = tid&127
//   blocks [64,..): histogram of tgt
// ---------------------------------------------------------------------------
__global__ __launch_bounds__(256) void fold_hist_kernel(
    const float* __restrict__ nw1, const float* __restrict__ nw2,
    const float* __restrict__ nb2, const float* __restrict__ ew2,
    const float* __restrict__ eb2, const float* __restrict__ mw1,
    const float* __restrict__ mb1, const float* __restrict__ mw2,
    const float* __restrict__ uw1, const float* __restrict__ uw2,
    const float* __restrict__ ew1,
    unsigned short* __restrict__ nw1t, unsigned short* __restrict__ wnt,
    unsigned short* __restrict__ wct, unsigned short* __restrict__ mw2t,
    unsigned short* __restrict__ uw1t, unsigned short* __restrict__ uw2t,
    unsigned short* __restrict__ ew1t8,
    float* __restrict__ bn, float* __restrict__ bc,
    const int* __restrict__ eidx, int* __restrict__ hist, int E) {
  if (blockIdx.x >= 64) {
    int e = (blockIdx.x - 64) * 256 + threadIdx.x;
    if (e < E) atomicAdd(&hist[eidx[E + e]], 1);
    return;
  }
  int b = blockIdx.x * 2 + (threadIdx.x >> 7);  // output col
  int t = threadIdx.x & 127;                    // input row
  float accn = 0.f, accc = 0.f;
  for (int j = 0; j < 128; ++j) {
    accn += nw2[t * 128 + j] * mw1[j * 128 + b];
    accc += ew2[t * 128 + j] * mw1[(128 + j) * 128 + b];
  }
  wnt[b * 128 + t] = f2bf(accn);
  wct[b * 128 + t] = f2bf(accc);
  nw1t[b * 128 + t] = f2bf(nw1[t * 128 + b]);
  mw2t[b * 128 + t] = f2bf(mw2[t * 128 + b]);
  uw1t[b * 128 + t] = f2bf(uw1[t * 128 + b]);
  uw2t[b * 128 + t] = f2bf(uw2[t * 128 + b]);
  if (t < 8) ew1t8[b * 8 + t] = (t < 6) ? f2bf(ew1[t * 128 + b]) : (unsigned short)0;
  if (b == 0) {
    float sn = 0.f, sc = 0.f;
    for (int j = 0; j < 128; ++j) {
      sn += nb2[j] * mw1[j * 128 + t];
      sc += eb2[j] * mw1[(128 + j) * 128 + t];
    }
    bn[t] = sn;
    bc[t] = mb1[t] + sc;
  }
}

__global__ __launch_bounds__(1024) void scan_kernel(const int* __restrict__ hist,
                                                    int* __restrict__ cursor, int G) {
  __shared__ int s[1024];
  int tid = threadIdx.x;
  int per = (G + 1023) >> 10;
  int b0 = tid * per;
  int sum = 0;
  for (int i = 0; i < per; ++i)
    if (b0 + i < G) sum += hist[b0 + i];
  s[tid] = sum;
  __syncthreads();
  for (int off = 1; off < 1024; off <<= 1) {
    int v = (tid >= off) ? s[tid - off] : 0;
    __syncthreads();
    s[tid] += v;
    __syncthreads();
  }
  int run = s[tid] - sum;  // exclusive prefix
  for (int i = 0; i < per; ++i)
    if (b0 + i < G) {
      cursor[b0 + i] = run;
      run += hist[b0 + i];
    }
}

// ---------------------------------------------------------------------------
// Merged scatter + node kernel (256 threads):
//   blocks [0,nScat):   scatter (src,tgt) into sorted position (atomic cursor)
//   blocks [nScat,..):  node MLP: node_pre = silu(x@nw1+nb1) @ Wn + bn
// ---------------------------------------------------------------------------
__global__ __launch_bounds__(256, 3) void scatter_node_kernel(
    const int* __restrict__ eidx, int* __restrict__ cursor,
    int2* __restrict__ st, int E, int nScat,
    const float* __restrict__ x, const float* __restrict__ nb1,
    const unsigned short* __restrict__ nw1t, const unsigned short* __restrict__ wnt,
    const float* __restrict__ bn, unsigned short* __restrict__ node_pre, int N) {
  __shared__ __align__(16) unsigned short s_x[128 * P];
  __shared__ __align__(16) float s_b1[128];
  __shared__ __align__(16) float s_bn[128];

  if (blockIdx.x < (unsigned)nScat) {
    int e = blockIdx.x * 256 + threadIdx.x;
    if (e < E) {
      int tg = eidx[E + e];
      int pos = atomicAdd(&cursor[tg], 1);
      st[pos] = make_int2(eidx[e], tg);
    }
    return;
  }

  int tid = threadIdx.x;
  long base = (long)(blockIdx.x - nScat) * 128;

#pragma unroll
  for (int i = 0; i < 16; ++i) {
    int flat = tid + i * 256;      // 4096 float4 = 128 rows x 32
    int row = flat >> 5;
    int c4 = (flat & 31) << 2;
    float4 v = make_float4(0.f, 0.f, 0.f, 0.f);
    if (base + row < N) v = *(const float4*)&x[(base + row) * 128 + c4];
    uint2 w; w.x = pack2bf(v.x, v.y); w.y = pack2bf(v.z, v.w);
    *(uint2*)&s_x[row * P + c4] = w;
  }
  if (tid < 128) { s_b1[tid] = nb1[tid]; s_bn[tid] = bn[tid]; }
  __syncthreads();

  int wave = tid >> 6, lane = tid & 63;
  int q = lane >> 4, l16 = lane & 15;
  int m0w = wave * 32;

  short8 a1[2][4];
  load_A128(nw1t, m0w, l16, q, a1);
  f32x4 acc[2][8];
#pragma unroll
  for (int rt = 0; rt < 2; ++rt)
#pragma unroll
    for (int ct = 0; ct < 8; ++ct) acc[rt][ct] = (f32x4){0.f, 0.f, 0.f, 0.f};
  gemm_T(a1, s_x, l16, q, acc);
  __syncthreads();
  epilogue_T<true>(acc, s_b1, s_x, m0w, l16, q);
  __syncthreads();

  short8 a2[2][4];
  load_A128(wnt, m0w, l16, q, a2);
#pragma unroll
  for (int rt = 0; rt < 2; ++rt)
#pragma unroll
    for (int ct = 0; ct < 8; ++ct) acc[rt][ct] = (f32x4){0.f, 0.f, 0.f, 0.f};
  gemm_T(a2, s_x, l16, q, acc);

  // store node_pre[node][feat] packed 8B
#pragma unroll
  for (int rt = 0; rt < 2; ++rt) {
    int f0 = m0w + rt * 16 + q * 4;
    float4 bv = *(const float4*)&s_bn[f0];
#pragma unroll
    for (int ct = 0; ct < 8; ++ct) {
      long n = base + ct * 16 + l16;
      if (n < N) {
        uint2 w;
        w.x = pack2bf(acc[rt][ct][0] + bv.x, acc[rt][ct][1] + bv.y);
        w.y = pack2bf(acc[rt][ct][2] + bv.z, acc[rt][ct][3] + bv.w);
        *(uint2*)&node_pre[n * 128 + f0] = w;
      }
    }
  }
}

// ---------------------------------------------------------------------------
// Edge kernel (sorted edges, transposed GEMMs), 128 edges / 256 threads.
//   attr(K=8) --MFMA--> h1 = silu(.+eb1)        (ew1^T as A, q==0 lanes)
//   acc := node_pre[src] (identity-A injection MFMA, b128 gathers)
//   acc += Wc^T · h1^T ; h2 = silu(acc + bc)
//   segmented reduction over sorted tgt runs -> atomicAdd sums (h2-space;
//   mw2 applied in grid_kernel by linearity of mean).
// LDS 36.9 KB -> 4 blocks/CU (LDS-capped), weights in registers.
// ---------------------------------------------------------------------------
__global__ __launch_bounds__(256, 3) void edge_kernel(
    const int2* __restrict__ st_sorted, const float* __restrict__ node_pos,
    const float* __restrict__ grid_pos, const float* __restrict__ ori,
    const unsigned short* __restrict__ ew1t8, const float* __restrict__ eb1,
    const unsigned short* __restrict__ wct, const float* __restrict__ bc,
    const unsigned short* __restrict__ node_pre, float* __restrict__ sums, int E) {
  __shared__ __align__(16) unsigned short s_h[128 * P];
  __shared__ int s_src[128];
  __shared__ int s_tgt[128];
  __shared__ __align__(16) float s_eb1[128];
  __shared__ __align__(16) float s_bc[128];

  int tid = threadIdx.x;
  int base = blockIdx.x * 128;

  if (tid < 128) {
    s_eb1[tid] = eb1[tid];
    s_bc[tid] = bc[tid];
    int eg = base + tid;
    int s = 0, tg = -1;
    float a0 = 0.f, a1 = 0.f, a2 = 0.f, a3 = 0.f, a4 = 0.f, a5 = 0.f;
    if (eg < E) {
      int2 st = st_sorted[eg];
      s = st.x; tg = st.y;
      // vectorized gathers (dwordx4 needs only dword alignment on CDNA)
      float2 p01 = *(const float2*)&node_pos[s * 3];
      float pz = node_pos[s * 3 + 2];
      float2 g01 = *(const float2*)&grid_pos[tg * 3];
      float gz = grid_pos[tg * 3 + 2];
      float4 o0 = *(const float4*)&ori[(long)s * 9];      // o[0..3]
      float4 o1 = *(const float4*)&ori[(long)s * 9 + 4];  // o[4..7]
      float o8 = ori[(long)s * 9 + 8];
      float rx = g01.x - p01.x, ry = g01.y - p01.y, rz = gz - pz;
      a0 = p01.x; a1 = p01.y; a2 = pz;
      a3 = rx * o0.x + ry * o0.w + rz * o1.z;   // o0,o3,o6
      a4 = rx * o0.y + ry * o1.x + rz * o1.w;   // o1,o4,o7
      a5 = rx * o0.z + ry * o1.y + rz * o8;     // o2,o5,o8
    }
    s_src[tid] = s;
    s_tgt[tid] = tg;
    uint4 w0;
    w0.x = pack2bf(a0, a1); w0.y = pack2bf(a2, a3); w0.z = pack2bf(a4, a5); w0.w = 0u;
    *(uint4*)&s_h[tid * P] = w0;   // attr row [edge][k0..7]
  }
  __syncthreads();

  int wave = tid >> 6, lane = tid & 63;
  int q = lane >> 4, l16 = lane & 15;
  int m0w = wave * 32;
  short8 z8 = (short8){0, 0, 0, 0, 0, 0, 0, 0};

  // Wc^T rows for this wave -> registers (L2-resident)
  short8 awc[2][4];
  load_A128(wct, m0w, l16, q, awc);

  // ew1^T rows (K=8) -> registers, q==0 lanes only
  short8 ae0 = z8, ae1 = z8;
  if (q == 0) {
    ae0 = *(const short8*)&ew1t8[(m0w + l16) * 8];
    ae1 = *(const short8*)&ew1t8[(m0w + 16 + l16) * 8];
  }

  // GEMM0: D[h][edge] = ew1^T · attr^T  (single K-tile)
  f32x4 acc0[2][8];
#pragma unroll
  for (int rt = 0; rt < 2; ++rt)
#pragma unroll
    for (int ct = 0; ct < 8; ++ct) acc0[rt][ct] = (f32x4){0.f, 0.f, 0.f, 0.f};
#pragma unroll
  for (int ct = 0; ct < 8; ++ct) {
    short8 b = z8;
    if (q == 0) b = *(const short8*)&s_h[(ct * 16 + l16) * P];
    acc0[0][ct] = __builtin_amdgcn_mfma_f32_16x16x32_bf16(ae0, b, acc0[0][ct], 0, 0, 0);
    acc0[1][ct] = __builtin_amdgcn_mfma_f32_16x16x32_bf16(ae1, b, acc0[1][ct], 0, 0, 0);
  }
  __syncthreads();  // attr reads done before overwrite

  epilogue_T<true>(acc0, s_eb1, s_h, m0w, l16, q);   // h1 -> s_h[edge][feat]
  __syncthreads();

  // acc := node_pre[src[edge]][feat]  via identity-A MFMA (b128 gathers)
  short8 aI;
#pragma unroll
  for (int j = 0; j < 8; ++j)
    aI[j] = ((q * 8 + j) == l16) ? (short)0x3F80 : (short)0;
  f32x4 acc[2][8];
#pragma unroll
  for (int ct = 0; ct < 8; ++ct) {
    long srow = (long)s_src[ct * 16 + l16] * 128;
#pragma unroll
    for (int rt = 0; rt < 2; ++rt) {
      short8 bnp = z8;
      if (q < 2) bnp = *(const short8*)&node_pre[srow + m0w + rt * 16 + q * 8];
      acc[rt][ct] = __builtin_amdgcn_mfma_f32_16x16x32_bf16(
          aI, bnp, (f32x4){0.f, 0.f, 0.f, 0.f}, 0, 0, 0);
    }
  }

  // GEMM1: acc += Wc^T · h1^T
  gemm_T(awc, s_h, l16, q, acc);
  __syncthreads();  // h1 reads done

  epilogue_T<true>(acc, s_bc, s_h, m0w, l16, q);     // h2 -> s_h[edge][feat]
  __syncthreads();

  // segmented reduction: thread = (colpair, 32-row chunk); flush per run.
  {
    int cp = tid & 63;
    int chunk = tid >> 6;       // 4 chunks x 32 rows
    int c0 = cp * 2;
    int row0 = chunk * 32;
    float v0 = 0.f, v1 = 0.f;
    int cur = s_tgt[row0];
    for (int r = 0; r < 32; ++r) {
      int row = row0 + r;
      int tg = s_tgt[row];
      if (tg != cur) {
        if (cur >= 0) {
          atomicAdd(&sums[(long)cur * 128 + c0], v0);
          atomicAdd(&sums[(long)cur * 128 + c0 + 1], v1);
        }
        v0 = 0.f; v1 = 0.f; cur = tg;
      }
      unsigned w = *(const unsigned*)&s_h[row * P + c0];
      v0 += bf2f((unsigned short)w);
      v1 += bf2f((unsigned short)(w >> 16));
    }
    if (cur >= 0) {
      atomicAdd(&sums[(long)cur * 128 + c0], v0);
      atomicAdd(&sums[(long)cur * 128 + c0 + 1], v1);
    }
  }
}

// ---------------------------------------------------------------------------
// Grid kernel (transposed): x = sums/clip(hist,1); y = x@mw2+mb2;
// out = silu(y@uw1+ub1)@uw2 + ub2.  Final store: packed float4.
// ---------------------------------------------------------------------------
__global__ __launch_bounds__(256, 3) void grid_kernel(
    const float* __restrict__ sums, const int* __restrict__ hist,
    const float* __restrict__ mb2, const float* __restrict__ ub1,
    const float* __restrict__ ub2, const unsigned short* __restrict__ mw2t,
    const unsigned short* __restrict__ uw1t, const unsigned short* __restrict__ uw2t,
    float* __restrict__ out, int G) {
  __shared__ __align__(16) unsigned short s_x[128 * P];
  __shared__ __align__(16) float s_bm[128];
  __shared__ __align__(16) float s_b1[128];
  __shared__ __align__(16) float s_b2[128];
  int tid = threadIdx.x;
  long base = (long)blockIdx.x * 128;

#pragma unroll
  for (int i = 0; i < 16; ++i) {
    int flat = tid + i * 256;       // 4096 float4 = 128 rows x 32
    int row = flat >> 5;
    int c4 = (flat & 31) << 2;
    float4 v = make_float4(0.f, 0.f, 0.f, 0.f);
    float inv = 1.f;
    if (base + row < G) {
      v = *(const float4*)&sums[(base + row) * 128 + c4];
      int c = hist[base + row];
      inv = __builtin_amdgcn_rcpf((float)(c < 1 ? 1 : c));
    }
    uint2 w; w.x = pack2bf(v.x * inv, v.y * inv); w.y = pack2bf(v.z * inv, v.w * inv);
    *(uint2*)&s_x[row * P + c4] = w;
  }
  if (tid < 128) { s_bm[tid] = mb2[tid]; s_b1[tid] = ub1[tid]; s_b2[tid] = ub2[tid]; }
  __syncthreads();

  int wave = tid >> 6, lane = tid & 63;
  int q = lane >> 4, l16 = lane & 15;
  int m0w = wave * 32;

  f32x4 acc[2][8];
  short8 aw[2][4];

  // GEMM A: grid_feat = x@mw2 + mb2 (no activation)
  load_A128(mw2t, m0w, l16, q, aw);
#pragma unroll
  for (int rt = 0; rt < 2; ++rt)
#pragma unroll
    for (int ct = 0; ct < 8; ++ct) acc[rt][ct] = (f32x4){0.f, 0.f, 0.f, 0.f};
  gemm_T(aw, s_x, l16, q, acc);
  __syncthreads();
  epilogue_T<false>(acc, s_bm, s_x, m0w, l16, q);
  __syncthreads();

  // GEMM B: silu(y@uw1 + ub1)
  load_A128(uw1t, m0w, l16, q, aw);
#pragma unroll
  for (int rt = 0; rt < 2; ++rt)
#pragma unroll
    for (int ct = 0; ct < 8; ++ct) acc[rt][ct] = (f32x4){0.f, 0.f, 0.f, 0.f};
  gemm_T(aw, s_x, l16, q, acc);
  __syncthreads();
  epilogue_T<true>(acc, s_b1, s_x, m0w, l16, q);
  __syncthreads();

  // GEMM C: out = h@uw2 + ub2  (fp32 float4 stores)
  load_A128(uw2t, m0w, l16, q, aw);
#pragma unroll
  for (int rt = 0; rt < 2; ++rt)
#pragma unroll
    for (int ct = 0; ct < 8; ++ct) acc[rt][ct] = (f32x4){0.f, 0.f, 0.f, 0.f};
  gemm_T(aw, s_x, l16, q, acc);

#pragma unroll
  for (int rt = 0; rt < 2; ++rt) {
    int f0 = m0w + rt * 16 + q * 4;
    float4 bv = *(const float4*)&s_b2[f0];
#pragma unroll
    for (int ct = 0; ct < 8; ++ct) {
      long g = base + ct * 16 + l16;
      if (g < G) {
        float4 o = make_float4(acc[rt][ct][0] + bv.x, acc[rt][ct][1] + bv.y,
                               acc[rt][ct][2] + bv.z, acc[rt][ct][3] + bv.w);
        *(float4*)&out[g * 128 + f0] = o;
      }
    }
  }
}

extern "C" void kernel_launch(void* const* d_in, const int* in_sizes, int n_in,
                              void* d_out, int out_size, void* d_ws, size_t ws_size,
                              hipStream_t stream) {
  const float* x    = (const float*)d_in[0];
  const float* npos = (const float*)d_in[1];
  const float* gpos = (const float*)d_in[2];
  const int*   eidx = (const int*)d_in[3];
  const float* ori  = (const float*)d_in[4];
  const float* nw1 = (const float*)d_in[5];
  const float* nb1 = (const float*)d_in[6];
  const float* nw2 = (const float*)d_in[7];
  const float* nb2 = (const float*)d_in[8];
  const float* ew1 = (const float*)d_in[9];
  const float* eb1 = (const float*)d_in[10];
  const float* ew2 = (const float*)d_in[11];
  const float* eb2 = (const float*)d_in[12];
  const float* mw1 = (const float*)d_in[13];
  const float* mb1 = (const float*)d_in[14];
  const float* mw2 = (const float*)d_in[15];
  const float* mb2 = (const float*)d_in[16];
  const float* uw1 = (const float*)d_in[17];
  const float* ub1 = (const float*)d_in[18];
  const float* uw2 = (const float*)d_in[19];
  const float* ub2 = (const float*)d_in[20];

  int N = in_sizes[0] / 128;
  int G = in_sizes[2] / 3;
  int E = in_sizes[3] / 2;

  // ws layout within R1's proven footprint (~43 MB). Sorted-edge buffer
  // (E*8 = 8 MB) lives in d_out (16.8 MB) — dead until grid_kernel (last
  // launch); stream order makes the reuse safe.
  char* ws = (char*)d_ws;
  size_t off = 0;
  float* sums = (float*)(ws + off);            off += (size_t)G * 128 * 4;
  int* hist = (int*)(ws + off);                off += (size_t)G * 4;
  int* cursor = (int*)(ws + off);              off += (size_t)G * 4;
  unsigned short* node_pre = (unsigned short*)(ws + off); off += (size_t)N * 128 * 2;
  off = (off + 255) & ~(size_t)255;
  unsigned short* w_nw1t = (unsigned short*)(ws + off); off += 128 * 128 * 2;
  unsigned short* w_wnt  = (unsigned short*)(ws + off); off += 128 * 128 * 2;
  unsigned short* w_wct  = (unsigned short*)(ws + off); off += 128 * 128 * 2;
  unsigned short* w_mw2t = (unsigned short*)(ws + off); off += 128 * 128 * 2;
  unsigned short* w_uw1t = (unsigned short*)(ws + off); off += 128 * 128 * 2;
  unsigned short* w_uw2t = (unsigned short*)(ws + off); off += 128 * 128 * 2;
  unsigned short* w_ew1t8 = (unsigned short*)(ws + off); off += 128 * 8 * 2;
  float* bn = (float*)(ws + off); off += 128 * 4;
  float* bc = (float*)(ws + off); off += 128 * 4;

  int2* st_sorted = (int2*)d_out;   // scratch until grid_kernel overwrites it

  int nScat = (E + 255) / 256;
  int nNode = (N + 127) / 128;
  int nHist = (E + 255) / 256;

  // zero sums + hist (contiguous)
  hipMemsetAsync(sums, 0, ((size_t)G * 128 + G) * 4, stream);

  fold_hist_kernel<<<64 + nHist, 256, 0, stream>>>(
      nw1, nw2, nb2, ew2, eb2, mw1, mb1, mw2, uw1, uw2, ew1,
      w_nw1t, w_wnt, w_wct, w_mw2t, w_uw1t, w_uw2t, w_ew1t8, bn, bc,
      eidx, hist, E);
  scan_kernel<<<1, 1024, 0, stream>>>(hist, cursor, G);
  scatter_node_kernel<<<nScat + nNode, 256, 0, stream>>>(
      eidx, cursor, st_sorted, E, nScat,
      x, nb1, w_nw1t, w_wnt, bn, node_pre, N);
  edge_kernel<<<(E + 127) / 128, 256, 0, stream>>>(st_sorted, npos, gpos, ori,
                                                   w_ew1t8, eb1, w_wct, bc,
                                                   node_pre, sums, E);
  grid_kernel<<<(G + 127) / 128, 256, 0, stream>>>(sums, hist, mb2, ub1, ub2,
                                                   w_mw2t, w_uw1t, w_uw2t,
                                                   (float*)d_out, G);
}